// Round 6
// baseline (8757.628 us; speedup 1.0000x reference)
//
#include <hip/hip_runtime.h>
#include <hip/hip_bf16.h>
#include <math.h>

// Problem constants
#define SEQL   4096
#define NITEMS 512
#define HID    256
#define NLAY   16
#define QS     64      // ring slots (power of 2)
#define TPB    4       // timesteps per block in proj kernel

typedef float f4 __attribute__((ext_vector_type(4)));

// Workspace layout (float offsets)
#define P_OFF   ((size_t)0)                               // P[4][SEQL][HID]
#define H_OFF   (P_OFF + (size_t)4*SEQL*HID)              // Hring[4][NLAY][QS][HID]
#define AP_OFF  (H_OFF + (size_t)4*NLAY*QS*HID)           // Apart[4][NLAY][QS][HID]
#define HF_OFF  (AP_OFF + (size_t)4*NLAY*QS*HID)          // hfinal[4][HID]
#define FLAG_OFF_FLOATS (HF_OFF + (size_t)1024)
// flags: Hflag[64] | Aflag[64] | progA[64] | progB[64]  => 256 u32
#define NFLAGS 256

// ---------------------------------------------------------------------------
// Coherent (IF$-level, sc0 sc1) vector memory ops as inline asm so WE control
// the vmcnt ledger.
__device__ __forceinline__ f4 ld_coh_f4(const float* p) {
    f4 r;
    asm volatile("global_load_dwordx4 %0, %1, off sc0 sc1" : "=v"(r) : "v"(p));
    return r;
}
__device__ __forceinline__ f4 ld_plain_f4(const float* p) {
    f4 r;
    asm volatile("global_load_dwordx4 %0, %1, off" : "=v"(r) : "v"(p));
    return r;
}
__device__ __forceinline__ void st_coh_f4(float* p, f4 v) {
    asm volatile("global_store_dwordx4 %0, %1, off sc0 sc1" :: "v"(p), "v"(v) : "memory");
}
__device__ __forceinline__ void st_coh_u32(unsigned* p, unsigned v) {
    asm volatile("global_store_dword %0, %1, off sc0 sc1" :: "v"(p), "v"(v) : "memory");
}
__device__ __forceinline__ unsigned uload(const unsigned* p) {
    return __hip_atomic_load(p, __ATOMIC_RELAXED, __HIP_MEMORY_SCOPE_AGENT);
}
__device__ __forceinline__ void ustore(unsigned* p, unsigned v) {
    __hip_atomic_store(p, v, __ATOMIC_RELAXED, __HIP_MEMORY_SCOPE_AGENT);
}

#define SBAR()  { __builtin_amdgcn_s_barrier(); __builtin_amdgcn_sched_barrier(0); }
#define LGKM0() { asm volatile("s_waitcnt lgkmcnt(0)" ::: "memory"); __builtin_amdgcn_sched_barrier(0); }
#define VMW(N)  { asm volatile("s_waitcnt vmcnt(" #N ")" ::: "memory"); __builtin_amdgcn_sched_barrier(0); }
// Wait for this wave's vmem AND pin `reg` as an output of the wait, so the
// compiler cannot hoist any use of `reg` above the s_waitcnt (rule #18 class).
#define WAIT_PIN(reg) { asm volatile("s_waitcnt vmcnt(0)" : "+v"(reg) :: "memory"); \
                        __builtin_amdgcn_sched_barrier(0); }

// Spin until *p >= target. Sticky timeout -> bugs give wrong answers, not hangs.
__device__ __forceinline__ unsigned spin_ge(const unsigned* p, unsigned target, bool* dead) {
    unsigned v = uload(p);
    if (v >= target || *dead) return v;
    unsigned it = 0;
    while ((v = uload(p)) < target) {
        __builtin_amdgcn_s_sleep(1);
        if (++it > (1u << 20)) { *dead = true; break; }
    }
    return v;
}

// FMA phase, readlane edition: each lane carries ONE h element for its group's
// 64-wide k-chunk; the 64-way broadcast happens in-register via v_readlane
// (SGPR dest). LDS traffic per wave per step: 1 ds_read_b32 + 1 ds_write_b32,
// instead of 16 broadcast ds_read_b128 (the R4 LDS-pipe storm).
__device__ __forceinline__ void fma_phase_rl(float hreg, const float (&w)[64],
                                             float* part, int tid) {
    float acc0 = 0.f, acc1 = 0.f;
    #pragma unroll
    for (int kk = 0; kk < 64; kk += 2) {
        float hb0 = __int_as_float(__builtin_amdgcn_readlane(__float_as_int(hreg), kk));
        float hb1 = __int_as_float(__builtin_amdgcn_readlane(__float_as_int(hreg), kk + 1));
        acc0 = fmaf(hb0, w[kk],     acc0);
        acc1 = fmaf(hb1, w[kk + 1], acc1);
    }
    part[tid] = acc0 + acc1;
}

// ---------------------------------------------------------------------------
// Kernel 1: input projection P[c][t][j] = sum_k Wih0_c[j,k] * x[t,k,c]
__global__ __launch_bounds__(1024) void proj_kernel(
    const float* __restrict__ x, const float* __restrict__ Wlp,
    const float* __restrict__ Wlpv, float* __restrict__ P)
{
    __shared__ float xs[TPB][4][NITEMS];   // 32 KB
    const int tid = threadIdx.x;
    const int t0 = blockIdx.x * TPB;

    #pragma unroll
    for (int tt = 0; tt < TPB; ++tt) {
        const float2* src = (const float2*)(x + (size_t)(t0 + tt) * NITEMS * 4);
        float2 v = src[tid];
        int e = 2 * tid;
        xs[tt][e & 3][e >> 2]       = v.x;
        xs[tt][(e + 1) & 3][e >> 2] = v.y;
    }
    __syncthreads();

    const int c = tid >> 8, j = tid & 255;
    const float* W = (c == 1) ? Wlpv : Wlp;
    const float4* row = (const float4*)(W + (size_t)j * NITEMS);
    float acc[TPB] = {0.f, 0.f, 0.f, 0.f};
    #pragma unroll 4
    for (int k4 = 0; k4 < NITEMS / 4; ++k4) {
        float4 w = row[k4];
        #pragma unroll
        for (int tt = 0; tt < TPB; ++tt) {
            float4 xv = *(const float4*)(&xs[tt][c][k4 * 4]);
            acc[tt] = fmaf(w.x, xv.x, fmaf(w.y, xv.y, fmaf(w.z, xv.z, fmaf(w.w, xv.w, acc[tt]))));
        }
    }
    #pragma unroll
    for (int tt = 0; tt < TPB; ++tt)
        P[((size_t)c * SEQL + (t0 + tt)) * HID + j] = acc[tt];
}

// ---------------------------------------------------------------------------
// Flag semantics (two-late): flag value k certifies the publisher's data
// stores through step k-2 are visible (S(k-2) provably drained by the steady
// VMW(4) preceding F(k) in the publisher's wave0 ledger).
//
// One B timestep. Wave0 vmem order per step k: S(k), L(k+2), F(k>0).
#define B_STEP(T_, AREG, VN) {                                                  \
    const int t_ = (T_);                                                        \
    unsigned afv = 0xFFFFFFFFu, bpv = 0xFFFFFFFFu;                              \
    const bool needAf = has_af && (t_ + 2 < SEQL);                              \
    const unsigned afTgt = (unsigned)((t_ + 4 < SEQL) ? (t_ + 4) : SEQL);       \
    const bool needBp = ((t_ & 7) == 0) && (t_ >= QS);                          \
    if (tid == 256 && needAf)                                                   \
        asm volatile("global_load_dword %0, %1, off sc0 sc1" : "=v"(afv) : "v"(af)); \
    if (tid == 257 && needBp)                                                   \
        asm volatile("global_load_dword %0, %1, off sc0 sc1" : "=v"(bpv) : "v"(consProgA)); \
    float hreg_ = hhA[0][(c4 << 6) | lane];                                     \
    fma_phase_rl(hreg_, w, part, tid);                                          \
    if (tid == 256 && needAf) {                                                 \
        WAIT_PIN(afv);                                                          \
        if (afv < afTgt) spin_ge(af, afTgt, &dead);                             \
    }                                                                           \
    if (tid == 257 && needBp) {                                                 \
        WAIT_PIN(bpv);                                                          \
        if (bpv < (unsigned)(t_ - 56)) spin_ge(consProgA, (unsigned)(t_ - 56), &dead); \
    }                                                                           \
    if (tid == 320 && has_af && (t_ & 7) == 0 && t_ > 0)                        \
        ustore(myprogB, (unsigned)t_);                                          \
    LGKM0(); SBAR();                                                            \
    if (tid < 64) {                                                             \
        VMW(VN);                                                                \
        const f4* pq = (const f4*)part;                                         \
        f4 s = pq[tid] + pq[64 + tid] + pq[128 + tid] + pq[192 + tid];          \
        f4 tot = s + AREG + bias4;                                              \
        f4 h4;                                                                  \
        h4.x = tanhf(tot.x); h4.y = tanhf(tot.y);                               \
        h4.z = tanhf(tot.z); h4.w = tanhf(tot.w);                               \
        ((f4*)hhA[0])[tid] = h4;                                                \
        st_coh_f4(Hout + (size_t)(t_ & (QS - 1)) * HID + 4 * tid, h4);          \
        if (is_top && t_ == SEQL - 1) *(f4*)(hfin + 4 * tid) = h4;              \
        if (t_ + 2 < SEQL) {                                                    \
            AREG = l0 ? ld_plain_f4(Psrc + (size_t)(t_ + 2) * HID + 4 * tid)    \
                      : ld_coh_f4(ap + (size_t)((t_ + 2) & (QS - 1)) * HID + 4 * tid); \
        }                                                                       \
        LGKM0();                                                                \
    }                                                                           \
    SBAR();                                                                     \
    if (tid == 0 && t_ > 0) st_coh_u32(myHfl, (unsigned)t_);                    \
}

// One A timestep. Wave0 vmem order per step k: S(k), L(k+3), F(k>0).
#define A_STEP(T_, PREG, VN) {                                                  \
    const int t_ = (T_);                                                        \
    unsigned inv = 0xFFFFFFFFu, bpv = 0xFFFFFFFFu;                              \
    const bool needIn = (t_ + 3 < SEQL);                                        \
    const unsigned inTgt = (unsigned)((t_ + 5 < SEQL) ? (t_ + 5) : SEQL);       \
    const bool needBp = ((t_ & 7) == 0) && (t_ >= QS);                          \
    if (tid == 256 && needIn)                                                   \
        asm volatile("global_load_dword %0, %1, off sc0 sc1" : "=v"(inv) : "v"(inflag)); \
    if (tid == 257 && needBp)                                                   \
        asm volatile("global_load_dword %0, %1, off sc0 sc1" : "=v"(bpv) : "v"(consProgB)); \
    float hreg_ = hhA[(T_) & 1][(c4 << 6) | lane];                              \
    fma_phase_rl(hreg_, w, part, tid);                                          \
    if (tid == 256 && needIn) {                                                 \
        WAIT_PIN(inv);                                                          \
        if (inv < inTgt) spin_ge(inflag, inTgt, &dead);                         \
    }                                                                           \
    if (tid == 257 && needBp) {                                                 \
        WAIT_PIN(bpv);                                                          \
        if (bpv < (unsigned)(t_ - 56)) spin_ge(consProgB, (unsigned)(t_ - 56), &dead); \
    }                                                                           \
    if (tid == 320 && (t_ & 7) == 0 && t_ > 0)                                  \
        ustore(myprogA, (unsigned)t_);                                          \
    LGKM0(); SBAR();                                                            \
    if (tid < 64) {                                                             \
        VMW(VN);                                                                \
        const f4* pq = (const f4*)part;                                         \
        f4 s = pq[tid] + pq[64 + tid] + pq[128 + tid] + pq[192 + tid];          \
        st_coh_f4(Aout + (size_t)(t_ & (QS - 1)) * HID + 4 * tid, s);           \
        if (t_ + 1 < SEQL) ((f4*)hhA[(t_ + 1) & 1])[tid] = PREG;                \
        if (t_ + 3 < SEQL)                                                      \
            PREG = ld_coh_f4(Hin + (size_t)((t_ + 3) & (QS - 1)) * HID + 4 * tid); \
        LGKM0();                                                                \
    }                                                                           \
    SBAR();                                                                     \
    if (tid == 0 && t_ > 0) st_coh_u32(myAfl, (unsigned)t_);                    \
}

// ---------------------------------------------------------------------------
// Kernel 2: layer-pipelined RNN. 124 blocks = 4 chains x (16 B + 15 A).
__global__ __launch_bounds__(1024) void rnn_pipe(
    const float* __restrict__ lp_Wih,  const float* __restrict__ lp_Whh,
    const float* __restrict__ lp_bih,  const float* __restrict__ lp_bhh,
    const float* __restrict__ lpv_Wih, const float* __restrict__ lpv_Whh,
    const float* __restrict__ lpv_bih, const float* __restrict__ lpv_bhh,
    const float* __restrict__ P, float* __restrict__ Hring,
    float* __restrict__ Apart, float* __restrict__ hfinal,
    unsigned* __restrict__ Hflag, unsigned* __restrict__ Aflag,
    unsigned* __restrict__ progA, unsigned* __restrict__ progB)
{
    __shared__ float hhA[2][HID];
    __shared__ float part[1024];

    const int b = blockIdx.x;
    if (b >= 124) return;
    const int c = b / 31;
    const int r = b % 31;
    const int role = (r < NLAY) ? 0 : 1;            // 0 = B, 1 = A
    const int l = (r < NLAY) ? r : (r - NLAY + 1);  // A covers l = 1..15

    const float* Wih = (c == 1) ? lpv_Wih : lp_Wih;
    const float* Whh = (c == 1) ? lpv_Whh : lp_Whh;
    const float* bih = (c == 1) ? lpv_bih : lp_bih;
    const float* bhh = (c == 1) ? lpv_bhh : lp_bhh;

    const int tid = threadIdx.x;
    const int j = tid & 255, c4 = tid >> 8;   // c4 = 64-wide k-chunk id
    const int lane = tid & 63;
    bool dead = false;

    if (role == 0) {
        // ===================== B role =====================
        const bool l0     = (l == 0);
        const bool has_af = (l > 0);
        const bool is_top = (l == NLAY - 1);

        float w[64];
        {
            const f4* wrow = (const f4*)(Whh + ((size_t)l * HID + j) * HID + (size_t)c4 * 64);
            #pragma unroll
            for (int i = 0; i < 16; ++i) {
                f4 v = wrow[i];
                w[4*i+0] = v.x; w[4*i+1] = v.y; w[4*i+2] = v.z; w[4*i+3] = v.w;
            }
        }
        #pragma unroll
        for (int i = 0; i < 64; ++i) asm volatile("" : "+v"(w[i]));

        f4 bias4 = (f4)0.f;
        if (tid < 64) {
            bias4 = *(const f4*)(bih + l * HID + 4 * tid);
            bias4 += *(const f4*)(bhh + l * HID + 4 * tid);
        }

        const float*    Psrc     = P + (size_t)c * SEQL * HID;
        const float*    ap       = Apart + ((size_t)(c * NLAY + l) * QS) * HID;
        const unsigned* af       = Aflag + c * NLAY + l;
        unsigned*       myHfl    = Hflag + c * NLAY + l;
        unsigned*       myprogB  = progB + c * NLAY + l;
        const unsigned* consProgA = (l < NLAY - 1) ? (progA + c * NLAY + l + 1)
                                                   : (const unsigned*)myprogB;
        float*          Hout     = Hring + ((size_t)(c * NLAY + l) * QS) * HID;
        float*          hfin     = hfinal + (size_t)c * HID;

        // prologue: h(-1)=0; two-late legality for L(0),L(1) => af >= 3
        if (tid < 256) hhA[0][tid] = 0.f;
        if (has_af && tid == 256) spin_ge(af, 3u, &dead);
        LGKM0(); SBAR();
        f4 a0e = (f4)0.f, a0o = (f4)0.f;
        if (tid < 64) {
            a0e = l0 ? ld_plain_f4(Psrc + 4 * tid)       : ld_coh_f4(ap + 4 * tid);
            a0o = l0 ? ld_plain_f4(Psrc + HID + 4 * tid) : ld_coh_f4(ap + HID + 4 * tid);
        }

        B_STEP(0, a0e, 1);
        B_STEP(1, a0o, 2);
        B_STEP(2, a0e, 3);
        B_STEP(3, a0o, 4);
        for (int t2 = 4; t2 < SEQL - 4; t2 += 2) {
            B_STEP(t2,     a0e, 4);
            B_STEP(t2 + 1, a0o, 4);
        }
        B_STEP(SEQL - 4, a0e, 4);
        B_STEP(SEQL - 3, a0o, 4);
        B_STEP(SEQL - 2, a0e, 4);
        B_STEP(SEQL - 1, a0o, 3);

        if (tid < 64) { VMW(0); }
        SBAR();
        if (tid == 0) st_coh_u32(myHfl, (unsigned)SEQL);
    } else {
        // ===================== A role =====================
        float w[64];
        {
            const f4* wrow = (const f4*)(Wih + ((size_t)(l - 1) * HID + j) * HID + (size_t)c4 * 64);
            #pragma unroll
            for (int i = 0; i < 16; ++i) {
                f4 v = wrow[i];
                w[4*i+0] = v.x; w[4*i+1] = v.y; w[4*i+2] = v.z; w[4*i+3] = v.w;
            }
        }
        #pragma unroll
        for (int i = 0; i < 64; ++i) asm volatile("" : "+v"(w[i]));

        const float*    Hin       = Hring + ((size_t)(c * NLAY + (l - 1)) * QS) * HID;
        const unsigned* inflag    = Hflag + c * NLAY + (l - 1);
        float*          Aout      = Apart + ((size_t)(c * NLAY + l) * QS) * HID;
        unsigned*       myAfl     = Aflag + c * NLAY + l;
        unsigned*       myprogA   = progA + c * NLAY + l;
        const unsigned* consProgB = progB + c * NLAY + l;

        // prologue: two-late legality for L(0),L(1),L(2) => inflag >= 4
        if (tid == 256) spin_ge(inflag, 4u, &dead);
        SBAR();
        f4 pvE = (f4)0.f, pvO = (f4)0.f;
        if (tid < 64) {
            f4 tmp = ld_coh_f4(Hin + 4 * tid);
            pvO = ld_coh_f4(Hin + (size_t)1 * HID + 4 * tid);
            pvE = ld_coh_f4(Hin + (size_t)2 * HID + 4 * tid);
            VMW(2);
            ((f4*)hhA[0])[tid] = tmp;
            LGKM0();
        }
        SBAR();

        A_STEP(0, pvO, 1);
        A_STEP(1, pvE, 2);
        A_STEP(2, pvO, 3);
        A_STEP(3, pvE, 4);
        for (int t2 = 4; t2 < SEQL - 4; t2 += 2) {
            A_STEP(t2,     pvO, 4);
            A_STEP(t2 + 1, pvE, 4);
        }
        A_STEP(SEQL - 4, pvO, 4);
        A_STEP(SEQL - 3, pvE, 4);
        A_STEP(SEQL - 2, pvO, 3);
        A_STEP(SEQL - 1, pvE, 0);

        if (tid < 64) { VMW(0); }
        SBAR();
        if (tid == 0) st_coh_u32(myAfl, (unsigned)SEQL);
    }
}

// ---------------------------------------------------------------------------
// Kernel 3: out = fc_W @ concat(h0..h3) + fc_b
__global__ __launch_bounds__(1024) void fc_kernel(
    const float* __restrict__ hfinal, const float* __restrict__ fcW,
    const float* __restrict__ fcb, float* __restrict__ out)
{
    __shared__ float red[1024];
    const int tid = threadIdx.x;
    float v  = hfinal[tid];
    float p0 = fcW[tid] * v;
    float p1 = fcW[1024 + tid] * v;

    red[tid] = p0; __syncthreads();
    for (int st = 512; st > 0; st >>= 1) { if (tid < st) red[tid] += red[tid + st]; __syncthreads(); }
    if (tid == 0) out[0] = red[0] + fcb[0];
    __syncthreads();
    red[tid] = p1; __syncthreads();
    for (int st = 512; st > 0; st >>= 1) { if (tid < st) red[tid] += red[tid + st]; __syncthreads(); }
    if (tid == 0) out[1] = red[0] + fcb[1];
}

// ---------------------------------------------------------------------------
extern "C" void kernel_launch(void* const* d_in, const int* in_sizes, int n_in,
                              void* d_out, int out_size, void* d_ws, size_t ws_size,
                              hipStream_t stream)
{
    (void)in_sizes; (void)n_in; (void)out_size; (void)ws_size;
    const float* x        = (const float*)d_in[0];
    const float* lp_Wih0  = (const float*)d_in[1];
    const float* lp_Wih   = (const float*)d_in[2];
    const float* lp_Whh   = (const float*)d_in[3];
    const float* lp_bih   = (const float*)d_in[4];
    const float* lp_bhh   = (const float*)d_in[5];
    const float* lpv_Wih0 = (const float*)d_in[6];
    const float* lpv_Wih  = (const float*)d_in[7];
    const float* lpv_Whh  = (const float*)d_in[8];
    const float* lpv_bih  = (const float*)d_in[9];
    const float* lpv_bhh  = (const float*)d_in[10];
    const float* fcW      = (const float*)d_in[11];
    const float* fcb      = (const float*)d_in[12];

    float* ws      = (float*)d_ws;
    float* Pbuf    = ws + P_OFF;
    float* Hring   = ws + H_OFF;
    float* Apart   = ws + AP_OFF;
    float* hfinal  = ws + HF_OFF;
    unsigned* flags = (unsigned*)(ws + FLAG_OFF_FLOATS);

    hipMemsetAsync(flags, 0, NFLAGS * sizeof(unsigned), stream);

    proj_kernel<<<SEQL / TPB, 1024, 0, stream>>>(x, lp_Wih0, lpv_Wih0, Pbuf);

    rnn_pipe<<<124, 1024, 0, stream>>>(lp_Wih, lp_Whh, lp_bih, lp_bhh,
                                       lpv_Wih, lpv_Whh, lpv_bih, lpv_bhh,
                                       Pbuf, Hring, Apart, hfinal,
                                       flags, flags + 64, flags + 128, flags + 192);

    fc_kernel<<<1, 1024, 0, stream>>>(hfinal, fcW, fcb, (float*)d_out);
}

// Round 7
// 5196.088 us; speedup vs baseline: 1.6854x; 1.6854x over previous
//
#include <hip/hip_runtime.h>
#include <hip/hip_bf16.h>
#include <math.h>

// Problem constants
#define SEQL   4096
#define NITEMS 512
#define HID    256
#define NLAY   16
#define QS     64      // ring slots (power of 2) = 8 chunks of 8 steps
#define CHUNK  8
#define NCHUNK (SEQL / CHUNK)   // 512
#define TPB    4       // timesteps per block in proj kernel

typedef float f4 __attribute__((ext_vector_type(4)));

// Workspace layout (float offsets)
#define P_OFF   ((size_t)0)                               // P[4][SEQL][HID]
#define H_OFF   (P_OFF + (size_t)4*SEQL*HID)              // Hring[4][NLAY][QS][HID]
#define AP_OFF  (H_OFF + (size_t)4*NLAY*QS*HID)           // Apart[4][NLAY][QS][HID]
#define HF_OFF  (AP_OFF + (size_t)4*NLAY*QS*HID)          // hfinal[4][HID]
#define FLAG_OFF_FLOATS (HF_OFF + (size_t)1024)
// flags: Hflag[64] | Aflag[64]
#define NFLAGS 256

// ---------------------------------------------------------------------------
// Coherent (IF$-level, sc0 sc1) ops as inline asm.
__device__ __forceinline__ f4 ld_coh_f4(const float* p) {
    f4 r;
    asm volatile("global_load_dwordx4 %0, %1, off sc0 sc1" : "=v"(r) : "v"(p));
    return r;
}
__device__ __forceinline__ float ld_coh_b32(const float* p) {
    float r;
    asm volatile("global_load_dword %0, %1, off sc0 sc1" : "=v"(r) : "v"(p));
    return r;
}
__device__ __forceinline__ void st_coh_b32(float* p, float v) {
    asm volatile("global_store_dword %0, %1, off sc0 sc1" :: "v"(p), "v"(v) : "memory");
}
__device__ __forceinline__ void st_coh_u32(unsigned* p, unsigned v) {
    asm volatile("global_store_dword %0, %1, off sc0 sc1" :: "v"(p), "v"(v) : "memory");
}
__device__ __forceinline__ unsigned uload(const unsigned* p) {
    return __hip_atomic_load(p, __ATOMIC_RELAXED, __HIP_MEMORY_SCOPE_AGENT);
}

#define SBAR()  { __builtin_amdgcn_s_barrier(); __builtin_amdgcn_sched_barrier(0); }
#define LGKM0() { asm volatile("s_waitcnt lgkmcnt(0)" ::: "memory"); __builtin_amdgcn_sched_barrier(0); }
#define VMW0()  { asm volatile("s_waitcnt vmcnt(0)" ::: "memory"); __builtin_amdgcn_sched_barrier(0); }

// Spin until *p >= target. Sticky timeout -> bugs give wrong answers, not hangs.
__device__ __forceinline__ void spin_ge(const unsigned* p, unsigned target, bool* dead) {
    if (*dead) return;
    unsigned it = 0;
    while (uload(p) < target) {
        __builtin_amdgcn_s_sleep(1);
        if (++it > (1u << 20)) { *dead = true; break; }
    }
}

// FMA phase: each lane carries ONE h element of its 64-wide k-chunk; 64-way
// broadcast in-register via v_readlane. Writes partial to part[tid].
__device__ __forceinline__ void fma_phase_rl(float hreg, const float (&w)[64],
                                             float* part, int tid) {
    float acc0 = 0.f, acc1 = 0.f;
    #pragma unroll
    for (int kk = 0; kk < 64; kk += 2) {
        float hb0 = __int_as_float(__builtin_amdgcn_readlane(__float_as_int(hreg), kk));
        float hb1 = __int_as_float(__builtin_amdgcn_readlane(__float_as_int(hreg), kk + 1));
        acc0 = fmaf(hb0, w[kk],     acc0);
        acc1 = fmaf(hb1, w[kk + 1], acc1);
    }
    part[tid] = acc0 + acc1;
}

// ---------------------------------------------------------------------------
// Kernel 1: input projection P[c][t][j] = sum_k Wih0_c[j,k] * x[t,k,c]
__global__ __launch_bounds__(1024) void proj_kernel(
    const float* __restrict__ x, const float* __restrict__ Wlp,
    const float* __restrict__ Wlpv, float* __restrict__ P)
{
    __shared__ float xs[TPB][4][NITEMS];   // 32 KB
    const int tid = threadIdx.x;
    const int t0 = blockIdx.x * TPB;

    #pragma unroll
    for (int tt = 0; tt < TPB; ++tt) {
        const float2* src = (const float2*)(x + (size_t)(t0 + tt) * NITEMS * 4);
        float2 v = src[tid];
        int e = 2 * tid;
        xs[tt][e & 3][e >> 2]       = v.x;
        xs[tt][(e + 1) & 3][e >> 2] = v.y;
    }
    __syncthreads();

    const int c = tid >> 8, j = tid & 255;
    const float* W = (c == 1) ? Wlpv : Wlp;
    const float4* row = (const float4*)(W + (size_t)j * NITEMS);
    float acc[TPB] = {0.f, 0.f, 0.f, 0.f};
    #pragma unroll 4
    for (int k4 = 0; k4 < NITEMS / 4; ++k4) {
        float4 w = row[k4];
        #pragma unroll
        for (int tt = 0; tt < TPB; ++tt) {
            float4 xv = *(const float4*)(&xs[tt][c][k4 * 4]);
            acc[tt] = fmaf(w.x, xv.x, fmaf(w.y, xv.y, fmaf(w.z, xv.z, fmaf(w.w, xv.w, acc[tt]))));
        }
    }
    #pragma unroll
    for (int tt = 0; tt < TPB; ++tt)
        P[((size_t)c * SEQL + (t0 + tt)) * HID + j] = acc[tt];
}

// ---------------------------------------------------------------------------
// Kernel 2: layer-pipelined RNN, CHUNKED protocol. 124 blocks.
// Flag value k+1  <=>  publisher's chunk k (steps 8k..8k+7) stored AND drained.
__global__ __launch_bounds__(1024) void rnn_pipe(
    const float* __restrict__ lp_Wih,  const float* __restrict__ lp_Whh,
    const float* __restrict__ lp_bih,  const float* __restrict__ lp_bhh,
    const float* __restrict__ lpv_Wih, const float* __restrict__ lpv_Whh,
    const float* __restrict__ lpv_bih, const float* __restrict__ lpv_bhh,
    const float* __restrict__ P, float* __restrict__ Hring,
    float* __restrict__ Apart, float* __restrict__ hfinal,
    unsigned* __restrict__ Hflag, unsigned* __restrict__ Aflag)
{
    __shared__ __align__(16) float hh8[CHUNK][HID];   // A: 8-step h staging; B: hh8[0] = h(t-1)
    __shared__ __align__(16) float part[1024];

    const int b = blockIdx.x;
    if (b >= 124) return;
    const int c = b / 31;
    const int r = b % 31;
    const int role = (r < NLAY) ? 0 : 1;            // 0 = B, 1 = A
    const int l = (r < NLAY) ? r : (r - NLAY + 1);  // A covers l = 1..15

    const float* Wih = (c == 1) ? lpv_Wih : lp_Wih;
    const float* Whh = (c == 1) ? lpv_Whh : lp_Whh;
    const float* bih = (c == 1) ? lpv_bih : lp_bih;
    const float* bhh = (c == 1) ? lpv_bhh : lp_bhh;

    const int tid = threadIdx.x;
    const int j = tid & 255, c4 = tid >> 8;   // (j, k-chunk) ownership
    const int lane = tid & 63;
    bool dead = false;

    if (role == 0) {
        // ===================== B role =====================
        const bool l0     = (l == 0);
        const bool is_top = (l == NLAY - 1);

        float w[64];
        {
            const f4* wrow = (const f4*)(Whh + ((size_t)l * HID + j) * HID + (size_t)c4 * 64);
            #pragma unroll
            for (int i = 0; i < 16; ++i) {
                f4 v = wrow[i];
                w[4*i+0] = v.x; w[4*i+1] = v.y; w[4*i+2] = v.z; w[4*i+3] = v.w;
            }
        }
        #pragma unroll
        for (int i = 0; i < 64; ++i) asm volatile("" : "+v"(w[i]));

        float bias = 0.f;
        if (tid < 256) bias = bih[l * HID + tid] + bhh[l * HID + tid];

        const float*    Psrc   = P + (size_t)c * SEQL * HID;
        const float*    apbuf  = Apart + ((size_t)(c * NLAY + l) * QS) * HID;
        const unsigned* af     = Aflag + c * NLAY + l;
        unsigned*       myHfl  = Hflag + c * NLAY + l;                 // published by ALL l (backpressure for A(l))
        const unsigned* consA  = Aflag + c * NLAY + l + 1;             // valid when l<15
        float*          Hout   = Hring + ((size_t)(c * NLAY + l) * QS) * HID;
        float*          hfin   = hfinal + (size_t)c * HID;

        if (tid < 256) hh8[0][tid] = 0.f;
        LGKM0(); SBAR();

        for (int k = 0; k < NCHUNK; ++k) {
            // --- chunk-top handshake (once per 8 steps) ---
            if (tid == 0) {
                if (!l0) spin_ge(af, (unsigned)(k + 1), &dead);                    // input partials chunk k ready
                if (l < NLAY - 1 && k >= CHUNK) spin_ge(consA, (unsigned)(k - 7), &dead); // h-ring slot free
            }
            SBAR();
            // --- stage 8 input rows into registers ---
            float ap8[CHUNK];
            if (tid < 256) {
                if (l0) {
                    #pragma unroll
                    for (int s = 0; s < CHUNK; ++s)
                        ap8[s] = Psrc[(size_t)(CHUNK * k + s) * HID + tid];   // plain (read-only, compiler-managed)
                } else {
                    const int sbase = (k & 7) * CHUNK;
                    #pragma unroll
                    for (int s = 0; s < CHUNK; ++s)
                        ap8[s] = ld_coh_b32(apbuf + (size_t)(sbase + s) * HID + tid);
                    VMW0();
                }
            }
            // --- 8 pure-local inner steps ---
            #pragma unroll
            for (int s = 0; s < CHUNK; ++s) {
                float hreg = hh8[0][(c4 << 6) | lane];
                fma_phase_rl(hreg, w, part, tid);
                LGKM0(); SBAR();
                if (tid < 256) {
                    float tot = part[tid] + part[tid + 256] + part[tid + 512] + part[tid + 768]
                              + ap8[s] + bias;
                    float h = tanhf(tot);
                    hh8[0][tid] = h;
                    if (l < NLAY - 1)
                        st_coh_b32(Hout + (size_t)((k & 7) * CHUNK + s) * HID + tid, h);
                    else if (k == NCHUNK - 1 && s == CHUNK - 1)
                        st_coh_b32(hfin + tid, h);
                }
                LGKM0(); SBAR();
            }
            // --- drain + publish (once per chunk) ---
            VMW0(); SBAR();
            if (tid == 0) st_coh_u32(myHfl, (unsigned)(k + 1));
        }
    } else {
        // ===================== A role (l = 1..15) =====================
        float w[64];
        {
            const f4* wrow = (const f4*)(Wih + ((size_t)(l - 1) * HID + j) * HID + (size_t)c4 * 64);
            #pragma unroll
            for (int i = 0; i < 16; ++i) {
                f4 v = wrow[i];
                w[4*i+0] = v.x; w[4*i+1] = v.y; w[4*i+2] = v.z; w[4*i+3] = v.w;
            }
        }
        #pragma unroll
        for (int i = 0; i < 64; ++i) asm volatile("" : "+v"(w[i]));

        const float*    Hin    = Hring + ((size_t)(c * NLAY + (l - 1)) * QS) * HID;
        const unsigned* inflag = Hflag + c * NLAY + (l - 1);
        float*          Aout   = Apart + ((size_t)(c * NLAY + l) * QS) * HID;
        unsigned*       myAfl  = Aflag + c * NLAY + l;
        const unsigned* consB  = Hflag + c * NLAY + l;   // B(l) chunk flag = partial-ring consumption

        for (int k = 0; k < NCHUNK; ++k) {
            // --- chunk-top handshake ---
            if (tid == 0) {
                spin_ge(inflag, (unsigned)(k + 1), &dead);                        // h chunk k ready
                if (k >= CHUNK) spin_ge(consB, (unsigned)(k - 7), &dead);         // partial-ring slot free
            }
            SBAR();
            // --- stage 8 h-vectors (2048 floats) into LDS ---
            if (tid < 512) {
                f4 v = ld_coh_f4(Hin + (size_t)(k & 7) * CHUNK * HID + 4 * tid);
                VMW0();
                *(f4*)&(((float*)hh8)[4 * tid]) = v;
            }
            LGKM0(); SBAR();
            // --- 8 pure-local inner steps ---
            #pragma unroll
            for (int s = 0; s < CHUNK; ++s) {
                float hreg = hh8[s][(c4 << 6) | lane];
                fma_phase_rl(hreg, w, part, tid);
                LGKM0(); SBAR();
                if (tid < 256) {
                    float tot = part[tid] + part[tid + 256] + part[tid + 512] + part[tid + 768];
                    st_coh_b32(Aout + (size_t)((k & 7) * CHUNK + s) * HID + tid, tot);
                }
                SBAR();
            }
            // --- drain + publish ---
            VMW0(); SBAR();
            if (tid == 0) st_coh_u32(myAfl, (unsigned)(k + 1));
        }
    }
}

// ---------------------------------------------------------------------------
// Kernel 3: out = fc_W @ concat(h0..h3) + fc_b
__global__ __launch_bounds__(1024) void fc_kernel(
    const float* __restrict__ hfinal, const float* __restrict__ fcW,
    const float* __restrict__ fcb, float* __restrict__ out)
{
    __shared__ float red[1024];
    const int tid = threadIdx.x;
    float v  = hfinal[tid];
    float p0 = fcW[tid] * v;
    float p1 = fcW[1024 + tid] * v;

    red[tid] = p0; __syncthreads();
    for (int st = 512; st > 0; st >>= 1) { if (tid < st) red[tid] += red[tid + st]; __syncthreads(); }
    if (tid == 0) out[0] = red[0] + fcb[0];
    __syncthreads();
    red[tid] = p1; __syncthreads();
    for (int st = 512; st > 0; st >>= 1) { if (tid < st) red[tid] += red[tid + st]; __syncthreads(); }
    if (tid == 0) out[1] = red[0] + fcb[1];
}

// ---------------------------------------------------------------------------
extern "C" void kernel_launch(void* const* d_in, const int* in_sizes, int n_in,
                              void* d_out, int out_size, void* d_ws, size_t ws_size,
                              hipStream_t stream)
{
    (void)in_sizes; (void)n_in; (void)out_size; (void)ws_size;
    const float* x        = (const float*)d_in[0];
    const float* lp_Wih0  = (const float*)d_in[1];
    const float* lp_Wih   = (const float*)d_in[2];
    const float* lp_Whh   = (const float*)d_in[3];
    const float* lp_bih   = (const float*)d_in[4];
    const float* lp_bhh   = (const float*)d_in[5];
    const float* lpv_Wih0 = (const float*)d_in[6];
    const float* lpv_Wih  = (const float*)d_in[7];
    const float* lpv_Whh  = (const float*)d_in[8];
    const float* lpv_bih  = (const float*)d_in[9];
    const float* lpv_bhh  = (const float*)d_in[10];
    const float* fcW      = (const float*)d_in[11];
    const float* fcb      = (const float*)d_in[12];

    float* ws      = (float*)d_ws;
    float* Pbuf    = ws + P_OFF;
    float* Hring   = ws + H_OFF;
    float* Apart   = ws + AP_OFF;
    float* hfinal  = ws + HF_OFF;
    unsigned* flags = (unsigned*)(ws + FLAG_OFF_FLOATS);

    hipMemsetAsync(flags, 0, NFLAGS * sizeof(unsigned), stream);

    proj_kernel<<<SEQL / TPB, 1024, 0, stream>>>(x, lp_Wih0, lpv_Wih0, Pbuf);

    rnn_pipe<<<124, 1024, 0, stream>>>(lp_Wih, lp_Whh, lp_bih, lp_bhh,
                                       lpv_Wih, lpv_Whh, lpv_bih, lpv_bhh,
                                       Pbuf, Hring, Apart, hfinal,
                                       flags, flags + 64);

    fc_kernel<<<1, 1024, 0, stream>>>(hfinal, fcW, fcb, (float*)d_out);
}

// Round 8
// 5129.592 us; speedup vs baseline: 1.7073x; 1.0130x over previous
//
#include <hip/hip_runtime.h>
#include <hip/hip_bf16.h>
#include <math.h>

// Problem constants
#define SEQL   4096
#define NITEMS 512
#define HID    256
#define NLAY   16
#define QS     64      // ring slots (power of 2) = 8 chunks of 8 steps
#define CHUNK  8
#define NCHUNK (SEQL / CHUNK)   // 512
#define TPB    4       // timesteps per block in proj kernel

typedef float f4 __attribute__((ext_vector_type(4)));

// Workspace layout (float offsets)
#define P_OFF   ((size_t)0)                               // P[4][SEQL][HID]
#define H_OFF   (P_OFF + (size_t)4*SEQL*HID)              // Hring[4][NLAY][QS][HID]
#define AP_OFF  (H_OFF + (size_t)4*NLAY*QS*HID)           // Apart[4][NLAY][QS][HID]
#define HF_OFF  (AP_OFF + (size_t)4*NLAY*QS*HID)          // hfinal[4][HID]
#define FLAG_OFF_FLOATS (HF_OFF + (size_t)1024)
// flags: Hflag[64] | Aflag[64]
#define NFLAGS 256

// ---------------------------------------------------------------------------
// Coherent (IF$-level, sc0 sc1) ops as inline asm.
__device__ __forceinline__ float ld_coh_b32(const float* p) {
    float r;
    asm volatile("global_load_dword %0, %1, off sc0 sc1" : "=v"(r) : "v"(p));
    return r;
}
__device__ __forceinline__ void st_coh_b32(float* p, float v) {
    asm volatile("global_store_dword %0, %1, off sc0 sc1" :: "v"(p), "v"(v) : "memory");
}
__device__ __forceinline__ void st_coh_u32(unsigned* p, unsigned v) {
    asm volatile("global_store_dword %0, %1, off sc0 sc1" :: "v"(p), "v"(v) : "memory");
}
__device__ __forceinline__ unsigned uload(const unsigned* p) {
    return __hip_atomic_load(p, __ATOMIC_RELAXED, __HIP_MEMORY_SCOPE_AGENT);
}

#define SBAR()  { __builtin_amdgcn_s_barrier(); __builtin_amdgcn_sched_barrier(0); }
#define LGKM0() { asm volatile("s_waitcnt lgkmcnt(0)" ::: "memory"); __builtin_amdgcn_sched_barrier(0); }
#define VMW0()  { asm volatile("s_waitcnt vmcnt(0)" ::: "memory"); __builtin_amdgcn_sched_barrier(0); }

// Spin until *p >= target. Sticky timeout -> bugs give wrong answers, not hangs.
__device__ __forceinline__ void spin_ge(const unsigned* p, unsigned target, bool* dead) {
    if (*dead) return;
    unsigned it = 0;
    while (uload(p) < target) {
        __builtin_amdgcn_s_sleep(1);
        if (++it > (1u << 20)) { *dead = true; break; }
    }
}

// Fast tanh: 1 - 2/(e^{2x}+1). v_exp + v_rcp, saturates correctly for |x| large.
__device__ __forceinline__ float tanh_fast(float x) {
    return 1.f - __fdividef(2.f, __expf(2.f * x) + 1.f);
}

// FMA phase: each lane carries ONE h element of its 64-wide k-chunk; 64-way
// broadcast in-register via v_readlane. Writes partial to part[tid].
__device__ __forceinline__ void fma_phase_rl(float hreg, const float (&w)[64],
                                             float* part, int tid) {
    float acc0 = 0.f, acc1 = 0.f;
    #pragma unroll
    for (int kk = 0; kk < 64; kk += 2) {
        float hb0 = __int_as_float(__builtin_amdgcn_readlane(__float_as_int(hreg), kk));
        float hb1 = __int_as_float(__builtin_amdgcn_readlane(__float_as_int(hreg), kk + 1));
        acc0 = fmaf(hb0, w[kk],     acc0);
        acc1 = fmaf(hb1, w[kk + 1], acc1);
    }
    part[tid] = acc0 + acc1;
}

// ---------------------------------------------------------------------------
// Kernel 1: input projection P[c][t][j] = sum_k Wih0_c[j,k] * x[t,k,c]
__global__ __launch_bounds__(1024) void proj_kernel(
    const float* __restrict__ x, const float* __restrict__ Wlp,
    const float* __restrict__ Wlpv, float* __restrict__ P)
{
    __shared__ float xs[TPB][4][NITEMS];   // 32 KB
    const int tid = threadIdx.x;
    const int t0 = blockIdx.x * TPB;

    #pragma unroll
    for (int tt = 0; tt < TPB; ++tt) {
        const float2* src = (const float2*)(x + (size_t)(t0 + tt) * NITEMS * 4);
        float2 v = src[tid];
        int e = 2 * tid;
        xs[tt][e & 3][e >> 2]       = v.x;
        xs[tt][(e + 1) & 3][e >> 2] = v.y;
    }
    __syncthreads();

    const int c = tid >> 8, j = tid & 255;
    const float* W = (c == 1) ? Wlpv : Wlp;
    const float4* row = (const float4*)(W + (size_t)j * NITEMS);
    float acc[TPB] = {0.f, 0.f, 0.f, 0.f};
    #pragma unroll 4
    for (int k4 = 0; k4 < NITEMS / 4; ++k4) {
        float4 w = row[k4];
        #pragma unroll
        for (int tt = 0; tt < TPB; ++tt) {
            float4 xv = *(const float4*)(&xs[tt][c][k4 * 4]);
            acc[tt] = fmaf(w.x, xv.x, fmaf(w.y, xv.y, fmaf(w.z, xv.z, fmaf(w.w, xv.w, acc[tt]))));
        }
    }
    #pragma unroll
    for (int tt = 0; tt < TPB; ++tt)
        P[((size_t)c * SEQL + (t0 + tt)) * HID + j] = acc[tt];
}

// ---------------------------------------------------------------------------
// Kernel 2: layer-pipelined RNN, CHUNKED protocol, one barrier per inner step.
// Flag value k+1  <=>  publisher's chunk k (steps 8k..8k+7) stored AND drained.
// Each wave's lane L carries h[m], m=(group<<6)|L; readlane broadcasts it.
__global__ __launch_bounds__(1024) void rnn_pipe(
    const float* __restrict__ lp_Wih,  const float* __restrict__ lp_Whh,
    const float* __restrict__ lp_bih,  const float* __restrict__ lp_bhh,
    const float* __restrict__ lpv_Wih, const float* __restrict__ lpv_Whh,
    const float* __restrict__ lpv_bih, const float* __restrict__ lpv_bhh,
    const float* __restrict__ P, float* __restrict__ Hring,
    float* __restrict__ Apart, float* __restrict__ hfinal,
    unsigned* __restrict__ Hflag, unsigned* __restrict__ Aflag)
{
    __shared__ __align__(16) float part2[2][1024];   // double-buffered partials

    const int b = blockIdx.x;
    if (b >= 124) return;
    const int c = b / 31;
    const int r = b % 31;
    const int role = (r < NLAY) ? 0 : 1;            // 0 = B, 1 = A
    const int l = (r < NLAY) ? r : (r - NLAY + 1);  // A covers l = 1..15

    const float* Wih = (c == 1) ? lpv_Wih : lp_Wih;
    const float* Whh = (c == 1) ? lpv_Whh : lp_Whh;
    const float* bih = (c == 1) ? lpv_bih : lp_bih;
    const float* bhh = (c == 1) ? lpv_bhh : lp_bhh;

    const int tid  = threadIdx.x;
    const int j    = tid & 255;          // output row this thread's FMA serves
    const int c4   = tid >> 8;           // k-chunk (and h-group) id, 0..3
    const int lane = tid & 63;
    const int m    = (c4 << 6) | lane;   // h element this lane carries/reduces
    const bool first = ((tid & 192) == 0);  // first wave of each group
    bool dead = false;

    if (role == 0) {
        // ===================== B role =====================
        const bool l0     = (l == 0);
        const bool is_top = (l == NLAY - 1);

        float w[64];
        {
            const f4* wrow = (const f4*)(Whh + ((size_t)l * HID + j) * HID + (size_t)c4 * 64);
            #pragma unroll
            for (int i = 0; i < 16; ++i) {
                f4 v = wrow[i];
                w[4*i+0] = v.x; w[4*i+1] = v.y; w[4*i+2] = v.z; w[4*i+3] = v.w;
            }
        }
        #pragma unroll
        for (int i = 0; i < 64; ++i) asm volatile("" : "+v"(w[i]));

        const float bias_m = bih[l * HID + m] + bhh[l * HID + m];

        const float*    Psrc   = P + (size_t)c * SEQL * HID;
        const float*    apbuf  = Apart + ((size_t)(c * NLAY + l) * QS) * HID;
        const unsigned* af     = Aflag + c * NLAY + l;
        unsigned*       myHfl  = Hflag + c * NLAY + l;
        const unsigned* consA  = Aflag + c * NLAY + l + 1;   // valid when l<15
        float*          Hout   = Hring + ((size_t)(c * NLAY + l) * QS) * HID;
        float*          hfin   = hfinal + (size_t)c * HID;

        float hreg = 0.f;   // lane-local h[m](t-1)

        for (int k = 0; k < NCHUNK; ++k) {
            // --- chunk-top handshake (once per 8 steps) ---
            if (tid == 0) {
                if (!l0) spin_ge(af, (unsigned)(k + 1), &dead);
                if (l < NLAY - 1 && k >= CHUNK) spin_ge(consA, (unsigned)(k - 7), &dead);
            }
            SBAR();
            // --- stage 8 input values for column m into registers ---
            float ap8[CHUNK];
            if (l0) {
                #pragma unroll
                for (int s = 0; s < CHUNK; ++s)
                    ap8[s] = Psrc[(size_t)(CHUNK * k + s) * HID + m];
            } else {
                const int sbase = (k & 7) * CHUNK;
                #pragma unroll
                for (int s = 0; s < CHUNK; ++s)
                    ap8[s] = ld_coh_b32(apbuf + (size_t)(sbase + s) * HID + m);
                VMW0();
            }
            // --- 8 inner steps, ONE barrier each ---
            #pragma unroll
            for (int s = 0; s < CHUNK; ++s) {
                fma_phase_rl(hreg, w, &part2[s & 1][0], tid);
                LGKM0(); SBAR();
                const float* pb = &part2[s & 1][0];
                float p = pb[m] + pb[m + 256] + pb[m + 512] + pb[m + 768];
                hreg = tanh_fast(p + ap8[s] + bias_m);
                if (first) {
                    if (l < NLAY - 1)
                        st_coh_b32(Hout + (size_t)((k & 7) * CHUNK + s) * HID + m, hreg);
                    else if (k == NCHUNK - 1 && s == CHUNK - 1)
                        st_coh_b32(hfin + m, hreg);
                }
            }
            // --- drain + publish (once per chunk) ---
            if (first) VMW0();
            SBAR();
            if (tid == 0) st_coh_u32(myHfl, (unsigned)(k + 1));
        }
    } else {
        // ===================== A role (l = 1..15) =====================
        float w[64];
        {
            const f4* wrow = (const f4*)(Wih + ((size_t)(l - 1) * HID + j) * HID + (size_t)c4 * 64);
            #pragma unroll
            for (int i = 0; i < 16; ++i) {
                f4 v = wrow[i];
                w[4*i+0] = v.x; w[4*i+1] = v.y; w[4*i+2] = v.z; w[4*i+3] = v.w;
            }
        }
        #pragma unroll
        for (int i = 0; i < 64; ++i) asm volatile("" : "+v"(w[i]));

        const float*    Hin    = Hring + ((size_t)(c * NLAY + (l - 1)) * QS) * HID;
        const unsigned* inflag = Hflag + c * NLAY + (l - 1);
        float*          Aout   = Apart + ((size_t)(c * NLAY + l) * QS) * HID;
        unsigned*       myAfl  = Aflag + c * NLAY + l;
        const unsigned* consB  = Hflag + c * NLAY + l;

        for (int k = 0; k < NCHUNK; ++k) {
            // --- chunk-top handshake ---
            if (tid == 0) {
                spin_ge(inflag, (unsigned)(k + 1), &dead);
                if (k >= CHUNK) spin_ge(consB, (unsigned)(k - 7), &dead);
            }
            SBAR();
            // --- stage 8 h values for element m straight into registers ---
            float h8[CHUNK];
            {
                const float* hb = Hin + (size_t)(k & 7) * CHUNK * HID + m;
                #pragma unroll
                for (int s = 0; s < CHUNK; ++s)
                    h8[s] = ld_coh_b32(hb + (size_t)s * HID);
                VMW0();
            }
            // --- 8 inner steps, ONE barrier each ---
            #pragma unroll
            for (int s = 0; s < CHUNK; ++s) {
                fma_phase_rl(h8[s], w, &part2[s & 1][0], tid);
                LGKM0(); SBAR();
                const float* pb = &part2[s & 1][0];
                float p = pb[m] + pb[m + 256] + pb[m + 512] + pb[m + 768];
                if (first)
                    st_coh_b32(Aout + (size_t)((k & 7) * CHUNK + s) * HID + m, p);
            }
            // --- drain + publish ---
            if (first) VMW0();
            SBAR();
            if (tid == 0) st_coh_u32(myAfl, (unsigned)(k + 1));
        }
    }
}

// ---------------------------------------------------------------------------
// Kernel 3: out = fc_W @ concat(h0..h3) + fc_b
__global__ __launch_bounds__(1024) void fc_kernel(
    const float* __restrict__ hfinal, const float* __restrict__ fcW,
    const float* __restrict__ fcb, float* __restrict__ out)
{
    __shared__ float red[1024];
    const int tid = threadIdx.x;
    float v  = hfinal[tid];
    float p0 = fcW[tid] * v;
    float p1 = fcW[1024 + tid] * v;

    red[tid] = p0; __syncthreads();
    for (int st = 512; st > 0; st >>= 1) { if (tid < st) red[tid] += red[tid + st]; __syncthreads(); }
    if (tid == 0) out[0] = red[0] + fcb[0];
    __syncthreads();
    red[tid] = p1; __syncthreads();
    for (int st = 512; st > 0; st >>= 1) { if (tid < st) red[tid] += red[tid + st]; __syncthreads(); }
    if (tid == 0) out[1] = red[0] + fcb[1];
}

// ---------------------------------------------------------------------------
extern "C" void kernel_launch(void* const* d_in, const int* in_sizes, int n_in,
                              void* d_out, int out_size, void* d_ws, size_t ws_size,
                              hipStream_t stream)
{
    (void)in_sizes; (void)n_in; (void)out_size; (void)ws_size;
    const float* x        = (const float*)d_in[0];
    const float* lp_Wih0  = (const float*)d_in[1];
    const float* lp_Wih   = (const float*)d_in[2];
    const float* lp_Whh   = (const float*)d_in[3];
    const float* lp_bih   = (const float*)d_in[4];
    const float* lp_bhh   = (const float*)d_in[5];
    const float* lpv_Wih0 = (const float*)d_in[6];
    const float* lpv_Wih  = (const float*)d_in[7];
    const float* lpv_Whh  = (const float*)d_in[8];
    const float* lpv_bih  = (const float*)d_in[9];
    const float* lpv_bhh  = (const float*)d_in[10];
    const float* fcW      = (const float*)d_in[11];
    const float* fcb      = (const float*)d_in[12];

    float* ws      = (float*)d_ws;
    float* Pbuf    = ws + P_OFF;
    float* Hring   = ws + H_OFF;
    float* Apart   = ws + AP_OFF;
    float* hfinal  = ws + HF_OFF;
    unsigned* flags = (unsigned*)(ws + FLAG_OFF_FLOATS);

    hipMemsetAsync(flags, 0, NFLAGS * sizeof(unsigned), stream);

    proj_kernel<<<SEQL / TPB, 1024, 0, stream>>>(x, lp_Wih0, lpv_Wih0, Pbuf);

    rnn_pipe<<<124, 1024, 0, stream>>>(lp_Wih, lp_Whh, lp_bih, lp_bhh,
                                       lpv_Wih, lpv_Whh, lpv_bih, lpv_bhh,
                                       Pbuf, Hring, Apart, hfinal,
                                       flags, flags + 64);

    fc_kernel<<<1, 1024, 0, stream>>>(hfinal, fcW, fcb, (float*)d_out);
}

// Round 10
// 4704.650 us; speedup vs baseline: 1.8615x; 1.0903x over previous
//
#include <hip/hip_runtime.h>
#include <hip/hip_bf16.h>
#include <math.h>

#define SEQL   4096
#define NITEMS 512
#define HID    256
#define NLAY   16
#define QS     64      // ring slots = 8 chunks x 8 steps
#define CHUNK  8
#define NCHUNK (SEQL / CHUNK)
#define TPB    4

typedef float f4 __attribute__((ext_vector_type(4)));

// Workspace layout (float offsets)
#define P_OFF   ((size_t)0)                               // P[4][SEQL][HID]
#define H_OFF   (P_OFF + (size_t)4*SEQL*HID)              // Hring[4][NLAY][QS][HID]
#define AP_OFF  (H_OFF + (size_t)4*NLAY*QS*HID)           // Apart[4][NLAY][QS][HID]
#define HF_OFF  (AP_OFF + (size_t)4*NLAY*QS*HID)          // hfinal[4][HID]
#define FLAG_OFF_FLOATS (HF_OFF + (size_t)1024)
#define NFLAGS 256

// ---------------------------------------------------------------------------
__device__ __forceinline__ f4 ld_coh_f4(const float* p) {
    f4 r;
    asm volatile("global_load_dwordx4 %0, %1, off sc0 sc1" : "=v"(r) : "v"(p));
    return r;
}
__device__ __forceinline__ float ld_coh_b32(const float* p) {
    float r;
    asm volatile("global_load_dword %0, %1, off sc0 sc1" : "=v"(r) : "v"(p));
    return r;
}
__device__ __forceinline__ void st_coh_b32(float* p, float v) {
    asm volatile("global_store_dword %0, %1, off sc0 sc1" :: "v"(p), "v"(v) : "memory");
}
__device__ __forceinline__ void st_coh_u32(unsigned* p, unsigned v) {
    asm volatile("global_store_dword %0, %1, off sc0 sc1" :: "v"(p), "v"(v) : "memory");
}
__device__ __forceinline__ unsigned uload(const unsigned* p) {
    return __hip_atomic_load(p, __ATOMIC_RELAXED, __HIP_MEMORY_SCOPE_AGENT);
}

#define SBAR()  { __builtin_amdgcn_s_barrier(); __builtin_amdgcn_sched_barrier(0); }
#define LGKM0() { asm volatile("s_waitcnt lgkmcnt(0)" ::: "memory"); __builtin_amdgcn_sched_barrier(0); }
#define VMW0()  { asm volatile("s_waitcnt vmcnt(0)" ::: "memory"); __builtin_amdgcn_sched_barrier(0); }

__device__ __forceinline__ void spin_ge(const unsigned* p, unsigned target, bool* dead) {
    if (*dead) return;
    unsigned it = 0;
    while (uload(p) < target) {
        __builtin_amdgcn_s_sleep(1);
        if (++it > (1u << 20)) { *dead = true; break; }
    }
}

__device__ __forceinline__ float tanh_fast(float x) {
    return 1.f - __fdividef(2.f, __expf(2.f * x) + 1.f);
}

// DPP-FMA: broadcast inside the FMA issue. ROW_ROR:i => lane q reads src0 from
// lane (q-i)&15 (verified against the AMD DPP scan idiom: row_shr:k delivers
// lane n-k to lane n). Weights pre-permuted with (q-i)&15 to match.
#define FMAC0(ACC, HB, W) \
    asm volatile("v_fmac_f32 %0, %1, %2" : "+v"(ACC) : "v"(HB), "v"(W));
#define FMACR(ACC, HB, W, I) \
    asm volatile("v_fmac_f32_dpp %0, %1, %2 row_ror:" #I " row_mask:0xf bank_mask:0xf" \
                 : "+v"(ACC) : "v"(HB), "v"(W));

#define FMAC_BLOCK(HB, WB) \
    FMAC0(acc0, HB, w[WB+0])      FMACR(acc1, HB, w[WB+1], 1)   \
    FMACR(acc2, HB, w[WB+2], 2)   FMACR(acc3, HB, w[WB+3], 3)   \
    FMACR(acc0, HB, w[WB+4], 4)   FMACR(acc1, HB, w[WB+5], 5)   \
    FMACR(acc2, HB, w[WB+6], 6)   FMACR(acc3, HB, w[WB+7], 7)   \
    FMACR(acc0, HB, w[WB+8], 8)   FMACR(acc1, HB, w[WB+9], 9)   \
    FMACR(acc2, HB, w[WB+10], 10) FMACR(acc3, HB, w[WB+11], 11) \
    FMACR(acc0, HB, w[WB+12], 12) FMACR(acc1, HB, w[WB+13], 13) \
    FMACR(acc2, HB, w[WB+14], 14) FMACR(acc3, HB, w[WB+15], 15)

// ---------------------------------------------------------------------------
// Kernel 1: input projection P[c][t][j] = sum_k Wih0_c[j,k] * x[t,k,c]
__global__ __launch_bounds__(1024) void proj_kernel(
    const float* __restrict__ x, const float* __restrict__ Wlp,
    const float* __restrict__ Wlpv, float* __restrict__ P)
{
    __shared__ float xs[TPB][4][NITEMS];
    const int tid = threadIdx.x;
    const int t0 = blockIdx.x * TPB;

    #pragma unroll
    for (int tt = 0; tt < TPB; ++tt) {
        const float2* src = (const float2*)(x + (size_t)(t0 + tt) * NITEMS * 4);
        float2 v = src[tid];
        int e = 2 * tid;
        xs[tt][e & 3][e >> 2]       = v.x;
        xs[tt][(e + 1) & 3][e >> 2] = v.y;
    }
    __syncthreads();

    const int c = tid >> 8, j = tid & 255;
    const float* W = (c == 1) ? Wlpv : Wlp;
    const float4* row = (const float4*)(W + (size_t)j * NITEMS);
    float acc[TPB] = {0.f, 0.f, 0.f, 0.f};
    #pragma unroll 4
    for (int k4 = 0; k4 < NITEMS / 4; ++k4) {
        float4 w = row[k4];
        #pragma unroll
        for (int tt = 0; tt < TPB; ++tt) {
            float4 xv = *(const float4*)(&xs[tt][c][k4 * 4]);
            acc[tt] = fmaf(w.x, xv.x, fmaf(w.y, xv.y, fmaf(w.z, xv.z, fmaf(w.w, xv.w, acc[tt]))));
        }
    }
    #pragma unroll
    for (int tt = 0; tt < TPB; ++tt)
        P[((size_t)c * SEQL + (t0 + tt)) * HID + j] = acc[tt];
}

// ---------------------------------------------------------------------------
// Kernel 2: layer-pipelined RNN, chunked protocol (R8-proven), DPP matvec core.
__global__ __launch_bounds__(1024) void rnn_pipe(
    const float* __restrict__ lp_Wih,  const float* __restrict__ lp_Whh,
    const float* __restrict__ lp_bih,  const float* __restrict__ lp_bhh,
    const float* __restrict__ lpv_Wih, const float* __restrict__ lpv_Whh,
    const float* __restrict__ lpv_bih, const float* __restrict__ lpv_bhh,
    const float* __restrict__ P, float* __restrict__ Hring,
    float* __restrict__ Apart, float* __restrict__ hfinal,
    unsigned* __restrict__ Hflag, unsigned* __restrict__ Aflag)
{
    __shared__ __align__(16) float part2[2][1024];   // B uses [0]; A double-buffers
    __shared__ __align__(16) float hvec[HID];        // B: current h vector
    __shared__ __align__(16) float hstage[CHUNK * HID]; // A: chunk h staging
    __shared__ float ldspad[18000];                  // force 1 block/CU (>80KB total)

    const int b = blockIdx.x;
    if (b >= 124) return;
    const int tid = threadIdx.x;
    ldspad[tid] = 0.f;                               // keep pad alive (1 write)

    const int c = b / 31;
    const int r = b % 31;
    const int role = (r < NLAY) ? 0 : 1;
    const int l = (r < NLAY) ? r : (r - NLAY + 1);

    const float* Wih = (c == 1) ? lpv_Wih : lp_Wih;
    const float* Whh = (c == 1) ? lpv_Whh : lp_Whh;
    const float* bih = (c == 1) ? lpv_bih : lp_bih;
    const float* bhh = (c == 1) ? lpv_bhh : lp_bhh;

    const int j    = tid & 255;
    const int c4   = tid >> 8;
    const int lane = tid & 63;
    const int q    = lane & 15;
    const int m    = (c4 << 6) | lane;
    const int gbase = (c4 << 6) | q;        // hvec gather base (same across rows)
    const bool first = ((tid & 192) == 0);  // waves 0,4,8,12
    bool dead = false;

    if (role == 0) {
        // ===================== B role =====================
        const bool l0 = (l == 0);

        float w[64];
        {
            const float* Wrow = Whh + ((size_t)l * HID + j) * HID;
            #pragma unroll
            for (int bb = 0; bb < 4; ++bb)
                #pragma unroll
                for (int i = 0; i < 16; ++i)
                    w[bb * 16 + i] = Wrow[(c4 << 6) + bb * 16 + ((q - i) & 15)];
        }
        #pragma unroll
        for (int i = 0; i < 64; ++i) asm volatile("" : "+v"(w[i]));

        float bias_m = 0.f;
        if (first) bias_m = bih[l * HID + m] + bhh[l * HID + m];

        const float*    Psrc  = P + (size_t)c * SEQL * HID;
        const float*    apbuf = Apart + ((size_t)(c * NLAY + l) * QS) * HID;
        const unsigned* af    = Aflag + c * NLAY + l;
        unsigned*       myHfl = Hflag + c * NLAY + l;
        const unsigned* consA = Aflag + c * NLAY + l + 1;   // valid when l<15
        float*          Hout  = Hring + ((size_t)(c * NLAY + l) * QS) * HID;
        float*          hfin  = hfinal + (size_t)c * HID;

        float hb0 = 0.f, hb1 = 0.f, hb2 = 0.f, hb3 = 0.f;   // h(-1) = 0

        for (int k = 0; k < NCHUNK; ++k) {
            if (tid == 0) {
                if (!l0) spin_ge(af, (unsigned)(k + 1), &dead);
                if (l < NLAY - 1 && k >= CHUNK) spin_ge(consA, (unsigned)(k - 7), &dead);
            }
            SBAR();
            float ap8[CHUNK];
            if (first) {
                if (l0) {
                    #pragma unroll
                    for (int s = 0; s < CHUNK; ++s)
                        ap8[s] = Psrc[(size_t)(CHUNK * k + s) * HID + m];
                } else {
                    const int sbase = (k & 7) * CHUNK;
                    #pragma unroll
                    for (int s = 0; s < CHUNK; ++s)
                        ap8[s] = ld_coh_b32(apbuf + (size_t)(sbase + s) * HID + m);
                    VMW0();
                }
            }
            #pragma unroll
            for (int s = 0; s < CHUNK; ++s) {
                float acc0 = 0.f, acc1 = 0.f, acc2 = 0.f, acc3 = 0.f;
                FMAC_BLOCK(hb0, 0)
                FMAC_BLOCK(hb1, 16)
                FMAC_BLOCK(hb2, 32)
                FMAC_BLOCK(hb3, 48)
                part2[0][tid] = (acc0 + acc1) + (acc2 + acc3);
                LGKM0(); SBAR();
                if (first) {
                    const float* pb = &part2[0][0];
                    float p = pb[m] + pb[m + 256] + pb[m + 512] + pb[m + 768];
                    float h = tanh_fast(p + ap8[s] + bias_m);
                    hvec[m] = h;
                    if (l < NLAY - 1)
                        st_coh_b32(Hout + (size_t)((k & 7) * CHUNK + s) * HID + m, h);
                    else if (k == NCHUNK - 1 && s == CHUNK - 1)
                        st_coh_b32(hfin + m, h);
                    LGKM0();
                }
                SBAR();
                hb0 = hvec[gbase];      hb1 = hvec[gbase + 16];
                hb2 = hvec[gbase + 32]; hb3 = hvec[gbase + 48];
            }
            if (first) VMW0();
            SBAR();
            if (tid == 0) st_coh_u32(myHfl, (unsigned)(k + 1));
        }
    } else {
        // ===================== A role (l = 1..15) =====================
        float w[64];
        {
            const float* Wrow = Wih + ((size_t)(l - 1) * HID + j) * HID;
            #pragma unroll
            for (int bb = 0; bb < 4; ++bb)
                #pragma unroll
                for (int i = 0; i < 16; ++i)
                    w[bb * 16 + i] = Wrow[(c4 << 6) + bb * 16 + ((q - i) & 15)];
        }
        #pragma unroll
        for (int i = 0; i < 64; ++i) asm volatile("" : "+v"(w[i]));

        const float*    Hin    = Hring + ((size_t)(c * NLAY + (l - 1)) * QS) * HID;
        const unsigned* inflag = Hflag + c * NLAY + (l - 1);
        float*          Aout   = Apart + ((size_t)(c * NLAY + l) * QS) * HID;
        unsigned*       myAfl  = Aflag + c * NLAY + l;
        const unsigned* consB  = Hflag + c * NLAY + l;

        for (int k = 0; k < NCHUNK; ++k) {
            if (tid == 0) {
                spin_ge(inflag, (unsigned)(k + 1), &dead);
                if (k >= CHUNK) spin_ge(consB, (unsigned)(k - 7), &dead);
            }
            SBAR();
            if (tid < 512) {
                f4 v = ld_coh_f4(Hin + (size_t)(k & 7) * CHUNK * HID + 4 * tid);
                VMW0();
                ((f4*)hstage)[tid] = v;
                LGKM0();
            }
            SBAR();
            #pragma unroll
            for (int s = 0; s < CHUNK; ++s) {
                const float* hs = &hstage[s * HID];
                float hb0 = hs[gbase];      float hb1 = hs[gbase + 16];
                float hb2 = hs[gbase + 32]; float hb3 = hs[gbase + 48];
                float acc0 = 0.f, acc1 = 0.f, acc2 = 0.f, acc3 = 0.f;
                FMAC_BLOCK(hb0, 0)
                FMAC_BLOCK(hb1, 16)
                FMAC_BLOCK(hb2, 32)
                FMAC_BLOCK(hb3, 48)
                part2[s & 1][tid] = (acc0 + acc1) + (acc2 + acc3);
                LGKM0(); SBAR();
                if (first) {
                    const float* pb = &part2[s & 1][0];
                    float p = pb[m] + pb[m + 256] + pb[m + 512] + pb[m + 768];
                    st_coh_b32(Aout + (size_t)((k & 7) * CHUNK + s) * HID + m, p);
                }
            }
            if (first) VMW0();
            SBAR();
            if (tid == 0) st_coh_u32(myAfl, (unsigned)(k + 1));
        }
    }
}

// ---------------------------------------------------------------------------
// Kernel 3: out = fc_W @ concat(h0..h3) + fc_b
__global__ __launch_bounds__(1024) void fc_kernel(
    const float* __restrict__ hfinal, const float* __restrict__ fcW,
    const float* __restrict__ fcb, float* __restrict__ out)
{
    __shared__ float red[1024];
    const int tid = threadIdx.x;
    float v  = hfinal[tid];
    float p0 = fcW[tid] * v;
    float p1 = fcW[1024 + tid] * v;

    red[tid] = p0; __syncthreads();
    for (int st = 512; st > 0; st >>= 1) { if (tid < st) red[tid] += red[tid + st]; __syncthreads(); }
    if (tid == 0) out[0] = red[0] + fcb[0];
    __syncthreads();
    red[tid] = p1; __syncthreads();
    for (int st = 512; st > 0; st >>= 1) { if (tid < st) red[tid] += red[tid + st]; __syncthreads(); }
    if (tid == 0) out[1] = red[0] + fcb[1];
}

// ---------------------------------------------------------------------------
extern "C" void kernel_launch(void* const* d_in, const int* in_sizes, int n_in,
                              void* d_out, int out_size, void* d_ws, size_t ws_size,
                              hipStream_t stream)
{
    (void)in_sizes; (void)n_in; (void)out_size; (void)ws_size;
    const float* x        = (const float*)d_in[0];
    const float* lp_Wih0  = (const float*)d_in[1];
    const float* lp_Wih   = (const float*)d_in[2];
    const float* lp_Whh   = (const float*)d_in[3];
    const float* lp_bih   = (const float*)d_in[4];
    const float* lp_bhh   = (const float*)d_in[5];
    const float* lpv_Wih0 = (const float*)d_in[6];
    const float* lpv_Wih  = (const float*)d_in[7];
    const float* lpv_Whh  = (const float*)d_in[8];
    const float* lpv_bih  = (const float*)d_in[9];
    const float* lpv_bhh  = (const float*)d_in[10];
    const float* fcW      = (const float*)d_in[11];
    const float* fcb      = (const float*)d_in[12];

    float* ws      = (float*)d_ws;
    float* Pbuf    = ws + P_OFF;
    float* Hring   = ws + H_OFF;
    float* Apart   = ws + AP_OFF;
    float* hfinal  = ws + HF_OFF;
    unsigned* flags = (unsigned*)(ws + FLAG_OFF_FLOATS);

    hipMemsetAsync(flags, 0, NFLAGS * sizeof(unsigned), stream);

    proj_kernel<<<SEQL / TPB, 1024, 0, stream>>>(x, lp_Wih0, lpv_Wih0, Pbuf);

    rnn_pipe<<<124, 1024, 0, stream>>>(lp_Wih, lp_Whh, lp_bih, lp_bhh,
                                       lpv_Wih, lpv_Whh, lpv_bih, lpv_bhh,
                                       Pbuf, Hring, Apart, hfinal,
                                       flags, flags + 64);

    fc_kernel<<<1, 1024, 0, stream>>>(hfinal, fcW, fcb, (float*)d_out);
}

// Round 11
// 4286.035 us; speedup vs baseline: 2.0433x; 1.0977x over previous
//
#include <hip/hip_runtime.h>
#include <hip/hip_bf16.h>
#include <math.h>

#define SEQL   4096
#define NITEMS 512
#define HID    256
#define NLAY   16
#define QS     64      // ring slots = 8 chunks x 8 steps
#define CHUNK  8
#define NCHUNK (SEQL / CHUNK)
#define TPB    4

typedef float f4 __attribute__((ext_vector_type(4)));

// Workspace layout (float offsets)
#define P_OFF   ((size_t)0)                               // P[4][SEQL][HID]
#define H_OFF   (P_OFF + (size_t)4*SEQL*HID)              // Hring[4][NLAY][QS][HID]
#define AP_OFF  (H_OFF + (size_t)4*NLAY*QS*HID)           // Apart[4][NLAY][QS][HID]
#define HF_OFF  (AP_OFF + (size_t)4*NLAY*QS*HID)          // hfinal[4][HID]
#define FLAG_OFF_FLOATS (HF_OFF + (size_t)1024)
#define NFLAGS 256

// ---------------------------------------------------------------------------
__device__ __forceinline__ float ld_coh_b32(const float* p) {
    float r;
    asm volatile("global_load_dword %0, %1, off sc0 sc1" : "=v"(r) : "v"(p));
    return r;
}
__device__ __forceinline__ void st_coh_b32(float* p, float v) {
    asm volatile("global_store_dword %0, %1, off sc0 sc1" :: "v"(p), "v"(v) : "memory");
}
__device__ __forceinline__ void st_coh_u32(unsigned* p, unsigned v) {
    asm volatile("global_store_dword %0, %1, off sc0 sc1" :: "v"(p), "v"(v) : "memory");
}
__device__ __forceinline__ unsigned uload(const unsigned* p) {
    return __hip_atomic_load(p, __ATOMIC_RELAXED, __HIP_MEMORY_SCOPE_AGENT);
}

#define SBAR()  { __builtin_amdgcn_s_barrier(); __builtin_amdgcn_sched_barrier(0); }
#define LGKM0() { asm volatile("s_waitcnt lgkmcnt(0)" ::: "memory"); __builtin_amdgcn_sched_barrier(0); }
#define VMW0()  { asm volatile("s_waitcnt vmcnt(0)" ::: "memory"); __builtin_amdgcn_sched_barrier(0); }

__device__ __forceinline__ void spin_ge(const unsigned* p, unsigned target, bool* dead) {
    if (*dead) return;
    unsigned it = 0;
    while (uload(p) < target) {
        __builtin_amdgcn_s_sleep(1);
        if (++it > (1u << 20)) { *dead = true; break; }
    }
}

__device__ __forceinline__ float tanh_fast(float x) {
    return 1.f - __fdividef(2.f, __expf(2.f * x) + 1.f);
}

// DPP-FMA: ROW_ROR:i => lane q reads src0 from lane (q-i)&15 (verified R10).
// Weights pre-permuted with (q-i)&15 to match.
#define FMAC0(ACC, HB, W) \
    asm volatile("v_fmac_f32 %0, %1, %2" : "+v"(ACC) : "v"(HB), "v"(W));
#define FMACR(ACC, HB, W, I) \
    asm volatile("v_fmac_f32_dpp %0, %1, %2 row_ror:" #I " row_mask:0xf bank_mask:0xf" \
                 : "+v"(ACC) : "v"(HB), "v"(W));

#define FMAC_BLOCK(HB, WB) \
    FMAC0(acc0, HB, w[WB+0])      FMACR(acc1, HB, w[WB+1], 1)   \
    FMACR(acc2, HB, w[WB+2], 2)   FMACR(acc3, HB, w[WB+3], 3)   \
    FMACR(acc0, HB, w[WB+4], 4)   FMACR(acc1, HB, w[WB+5], 5)   \
    FMACR(acc2, HB, w[WB+6], 6)   FMACR(acc3, HB, w[WB+7], 7)   \
    FMACR(acc0, HB, w[WB+8], 8)   FMACR(acc1, HB, w[WB+9], 9)   \
    FMACR(acc2, HB, w[WB+10], 10) FMACR(acc3, HB, w[WB+11], 11) \
    FMACR(acc0, HB, w[WB+12], 12) FMACR(acc1, HB, w[WB+13], 13) \
    FMACR(acc2, HB, w[WB+14], 14) FMACR(acc3, HB, w[WB+15], 15)

// Broadcast h across the wave: lane l pulls lane (b*16 + (l&15)) of its OWN
// wave's h register via ds_bpermute (register crossbar, no LDS storage).
#define BPERM4(H) \
    { hb0 = __int_as_float(__builtin_amdgcn_ds_bpermute(ab0, __float_as_int(H))); \
      hb1 = __int_as_float(__builtin_amdgcn_ds_bpermute(ab1, __float_as_int(H))); \
      hb2 = __int_as_float(__builtin_amdgcn_ds_bpermute(ab2, __float_as_int(H))); \
      hb3 = __int_as_float(__builtin_amdgcn_ds_bpermute(ab3, __float_as_int(H))); }

// ---------------------------------------------------------------------------
// Kernel 1: input projection P[c][t][j] = sum_k Wih0_c[j,k] * x[t,k,c]
__global__ __launch_bounds__(1024) void proj_kernel(
    const float* __restrict__ x, const float* __restrict__ Wlp,
    const float* __restrict__ Wlpv, float* __restrict__ P)
{
    __shared__ float xs[TPB][4][NITEMS];
    const int tid = threadIdx.x;
    const int t0 = blockIdx.x * TPB;

    #pragma unroll
    for (int tt = 0; tt < TPB; ++tt) {
        const float2* src = (const float2*)(x + (size_t)(t0 + tt) * NITEMS * 4);
        float2 v = src[tid];
        int e = 2 * tid;
        xs[tt][e & 3][e >> 2]       = v.x;
        xs[tt][(e + 1) & 3][e >> 2] = v.y;
    }
    __syncthreads();

    const int c = tid >> 8, j = tid & 255;
    const float* W = (c == 1) ? Wlpv : Wlp;
    const float4* row = (const float4*)(W + (size_t)j * NITEMS);
    float acc[TPB] = {0.f, 0.f, 0.f, 0.f};
    #pragma unroll 4
    for (int k4 = 0; k4 < NITEMS / 4; ++k4) {
        float4 w = row[k4];
        #pragma unroll
        for (int tt = 0; tt < TPB; ++tt) {
            float4 xv = *(const float4*)(&xs[tt][c][k4 * 4]);
            acc[tt] = fmaf(w.x, xv.x, fmaf(w.y, xv.y, fmaf(w.z, xv.z, fmaf(w.w, xv.w, acc[tt]))));
        }
    }
    #pragma unroll
    for (int tt = 0; tt < TPB; ++tt)
        P[((size_t)c * SEQL + (t0 + tt)) * HID + j] = acc[tt];
}

// ---------------------------------------------------------------------------
// Kernel 2: layer-pipelined RNN. Chunked handshakes; ONE barrier per inner
// step; all-wave redundant reduce (h in-register on every wave); bpermute
// broadcast. 124 blocks = 4 chains x (16 B + 15 A).
__global__ __launch_bounds__(1024) void rnn_pipe(
    const float* __restrict__ lp_Wih,  const float* __restrict__ lp_Whh,
    const float* __restrict__ lp_bih,  const float* __restrict__ lp_bhh,
    const float* __restrict__ lpv_Wih, const float* __restrict__ lpv_Whh,
    const float* __restrict__ lpv_bih, const float* __restrict__ lpv_bhh,
    const float* __restrict__ P, float* __restrict__ Hring,
    float* __restrict__ Apart, float* __restrict__ hfinal,
    unsigned* __restrict__ Hflag, unsigned* __restrict__ Aflag)
{
    __shared__ __align__(16) float part2[2][1024];   // double-buffered partials

    const int b = blockIdx.x;
    if (b >= 124) return;
    const int tid = threadIdx.x;

    const int c = b / 31;
    const int r = b % 31;
    const int role = (r < NLAY) ? 0 : 1;
    const int l = (r < NLAY) ? r : (r - NLAY + 1);

    const float* Wih = (c == 1) ? lpv_Wih : lp_Wih;
    const float* Whh = (c == 1) ? lpv_Whh : lp_Whh;
    const float* bih = (c == 1) ? lpv_bih : lp_bih;
    const float* bhh = (c == 1) ? lpv_bhh : lp_bhh;

    const int j    = tid & 255;
    const int c4   = tid >> 8;
    const int lane = tid & 63;
    const int q    = lane & 15;
    const int m    = (c4 << 6) | lane;
    const bool first = ((tid & 192) == 0);  // waves 0,4,8,12
    bool dead = false;

    // bpermute byte-addresses: lane l pulls lane (b*16 + q)
    const int ab0 = 4 * (q);
    const int ab1 = 4 * (16 + q);
    const int ab2 = 4 * (32 + q);
    const int ab3 = 4 * (48 + q);

    if (role == 0) {
        // ===================== B role =====================
        const bool l0 = (l == 0);

        float w[64];
        {
            const float* Wrow = Whh + ((size_t)l * HID + j) * HID;
            #pragma unroll
            for (int bb = 0; bb < 4; ++bb)
                #pragma unroll
                for (int i = 0; i < 16; ++i)
                    w[bb * 16 + i] = Wrow[(c4 << 6) + bb * 16 + ((q - i) & 15)];
        }
        #pragma unroll
        for (int i = 0; i < 64; ++i) asm volatile("" : "+v"(w[i]));

        const float bias_m = bih[l * HID + m] + bhh[l * HID + m];

        const float*    Psrc  = P + (size_t)c * SEQL * HID;
        const float*    apbuf = Apart + ((size_t)(c * NLAY + l) * QS) * HID;
        const unsigned* af    = Aflag + c * NLAY + l;
        unsigned*       myHfl = Hflag + c * NLAY + l;
        const unsigned* consA = Aflag + c * NLAY + l + 1;   // valid when l<15
        float*          Hout  = Hring + ((size_t)(c * NLAY + l) * QS) * HID;
        float*          hfin  = hfinal + (size_t)c * HID;

        float h = 0.f;   // every wave carries h[m](t-1)
        float hb0, hb1, hb2, hb3;

        for (int k = 0; k < NCHUNK; ++k) {
            if (tid == 0) {
                if (!l0) spin_ge(af, (unsigned)(k + 1), &dead);
                if (l < NLAY - 1 && k >= CHUNK) spin_ge(consA, (unsigned)(k - 7), &dead);
            }
            SBAR();
            // stage 8 input values for element m (ALL waves; coalesced/multicast)
            float ap8[CHUNK];
            if (l0) {
                #pragma unroll
                for (int s = 0; s < CHUNK; ++s)
                    ap8[s] = Psrc[(size_t)(CHUNK * k + s) * HID + m];
            } else {
                const int sbase = (k & 7) * CHUNK;
                #pragma unroll
                for (int s = 0; s < CHUNK; ++s)
                    ap8[s] = ld_coh_b32(apbuf + (size_t)(sbase + s) * HID + m);
                VMW0();
            }
            // 8 inner steps, ONE barrier each
            #pragma unroll
            for (int s = 0; s < CHUNK; ++s) {
                BPERM4(h);
                float acc0 = 0.f, acc1 = 0.f, acc2 = 0.f, acc3 = 0.f;
                FMAC_BLOCK(hb0, 0)
                FMAC_BLOCK(hb1, 16)
                FMAC_BLOCK(hb2, 32)
                FMAC_BLOCK(hb3, 48)
                part2[s & 1][tid] = (acc0 + acc1) + (acc2 + acc3);
                LGKM0(); SBAR();
                const float* pb = &part2[s & 1][0];
                float p = pb[m] + pb[m + 256] + pb[m + 512] + pb[m + 768];
                h = tanh_fast(p + ap8[s] + bias_m);
                if (first) {
                    if (l < NLAY - 1)
                        st_coh_b32(Hout + (size_t)((k & 7) * CHUNK + s) * HID + m, h);
                    else if (k == NCHUNK - 1 && s == CHUNK - 1)
                        st_coh_b32(hfin + m, h);
                }
            }
            if (first) VMW0();
            SBAR();
            if (tid == 0) st_coh_u32(myHfl, (unsigned)(k + 1));
        }
    } else {
        // ===================== A role (l = 1..15) =====================
        float w[64];
        {
            const float* Wrow = Wih + ((size_t)(l - 1) * HID + j) * HID;
            #pragma unroll
            for (int bb = 0; bb < 4; ++bb)
                #pragma unroll
                for (int i = 0; i < 16; ++i)
                    w[bb * 16 + i] = Wrow[(c4 << 6) + bb * 16 + ((q - i) & 15)];
        }
        #pragma unroll
        for (int i = 0; i < 64; ++i) asm volatile("" : "+v"(w[i]));

        const float*    Hin    = Hring + ((size_t)(c * NLAY + (l - 1)) * QS) * HID;
        const unsigned* inflag = Hflag + c * NLAY + (l - 1);
        float*          Aout   = Apart + ((size_t)(c * NLAY + l) * QS) * HID;
        unsigned*       myAfl  = Aflag + c * NLAY + l;
        const unsigned* consB  = Hflag + c * NLAY + l;

        float hb0, hb1, hb2, hb3;

        for (int k = 0; k < NCHUNK; ++k) {
            if (tid == 0) {
                spin_ge(inflag, (unsigned)(k + 1), &dead);
                if (k >= CHUNK) spin_ge(consB, (unsigned)(k - 7), &dead);
            }
            SBAR();
            // stage 8 h values for element m straight into registers (coalesced)
            float h8[CHUNK];
            {
                const float* hbase = Hin + (size_t)(k & 7) * CHUNK * HID + m;
                #pragma unroll
                for (int s = 0; s < CHUNK; ++s)
                    h8[s] = ld_coh_b32(hbase + (size_t)s * HID);
                VMW0();
            }
            // 8 inner steps, ONE barrier each
            #pragma unroll
            for (int s = 0; s < CHUNK; ++s) {
                BPERM4(h8[s]);
                float acc0 = 0.f, acc1 = 0.f, acc2 = 0.f, acc3 = 0.f;
                FMAC_BLOCK(hb0, 0)
                FMAC_BLOCK(hb1, 16)
                FMAC_BLOCK(hb2, 32)
                FMAC_BLOCK(hb3, 48)
                part2[s & 1][tid] = (acc0 + acc1) + (acc2 + acc3);
                LGKM0(); SBAR();
                if (first) {
                    const float* pb = &part2[s & 1][0];
                    float p = pb[m] + pb[m + 256] + pb[m + 512] + pb[m + 768];
                    st_coh_b32(Aout + (size_t)((k & 7) * CHUNK + s) * HID + m, p);
                }
            }
            if (first) VMW0();
            SBAR();
            if (tid == 0) st_coh_u32(myAfl, (unsigned)(k + 1));
        }
    }
}

// ---------------------------------------------------------------------------
// Kernel 3: out = fc_W @ concat(h0..h3) + fc_b
__global__ __launch_bounds__(1024) void fc_kernel(
    const float* __restrict__ hfinal, const float* __restrict__ fcW,
    const float* __restrict__ fcb, float* __restrict__ out)
{
    __shared__ float red[1024];
    const int tid = threadIdx.x;
    float v  = hfinal[tid];
    float p0 = fcW[tid] * v;
    float p1 = fcW[1024 + tid] * v;

    red[tid] = p0; __syncthreads();
    for (int st = 512; st > 0; st >>= 1) { if (tid < st) red[tid] += red[tid + st]; __syncthreads(); }
    if (tid == 0) out[0] = red[0] + fcb[0];
    __syncthreads();
    red[tid] = p1; __syncthreads();
    for (int st = 512; st > 0; st >>= 1) { if (tid < st) red[tid] += red[tid + st]; __syncthreads(); }
    if (tid == 0) out[1] = red[0] + fcb[1];
}

// ---------------------------------------------------------------------------
extern "C" void kernel_launch(void* const* d_in, const int* in_sizes, int n_in,
                              void* d_out, int out_size, void* d_ws, size_t ws_size,
                              hipStream_t stream)
{
    (void)in_sizes; (void)n_in; (void)out_size; (void)ws_size;
    const float* x        = (const float*)d_in[0];
    const float* lp_Wih0  = (const float*)d_in[1];
    const float* lp_Wih   = (const float*)d_in[2];
    const float* lp_Whh   = (const float*)d_in[3];
    const float* lp_bih   = (const float*)d_in[4];
    const float* lp_bhh   = (const float*)d_in[5];
    const float* lpv_Wih0 = (const float*)d_in[6];
    const float* lpv_Wih  = (const float*)d_in[7];
    const float* lpv_Whh  = (const float*)d_in[8];
    const float* lpv_bih  = (const float*)d_in[9];
    const float* lpv_bhh  = (const float*)d_in[10];
    const float* fcW      = (const float*)d_in[11];
    const float* fcb      = (const float*)d_in[12];

    float* ws      = (float*)d_ws;
    float* Pbuf    = ws + P_OFF;
    float* Hring   = ws + H_OFF;
    float* Apart   = ws + AP_OFF;
    float* hfinal  = ws + HF_OFF;
    unsigned* flags = (unsigned*)(ws + FLAG_OFF_FLOATS);

    hipMemsetAsync(flags, 0, NFLAGS * sizeof(unsigned), stream);

    proj_kernel<<<SEQL / TPB, 1024, 0, stream>>>(x, lp_Wih0, lpv_Wih0, Pbuf);

    rnn_pipe<<<124, 1024, 0, stream>>>(lp_Wih, lp_Whh, lp_bih, lp_bhh,
                                       lpv_Wih, lpv_Whh, lpv_bih, lpv_bhh,
                                       Pbuf, Hring, Apart, hfinal,
                                       flags, flags + 64);

    fc_kernel<<<1, 1024, 0, stream>>>(hfinal, fcW, fcb, (float*)d_out);
}

// Round 12
// 3802.586 us; speedup vs baseline: 2.3031x; 1.1271x over previous
//
#include <hip/hip_runtime.h>
#include <hip/hip_bf16.h>
#include <math.h>

#define SEQL   4096
#define NITEMS 512
#define HID    256
#define NLAY   16
#define QS     64      // ring slots = 8 chunks x 8 steps
#define CHUNK  8
#define NCHUNK (SEQL / CHUNK)
#define TPB    4

typedef float f4 __attribute__((ext_vector_type(4)));

// Workspace layout (float offsets)
#define P_OFF   ((size_t)0)                               // P[4][SEQL][HID]
#define H_OFF   (P_OFF + (size_t)4*SEQL*HID)              // Hring[4][NLAY][QS][HID]
#define AP_OFF  (H_OFF + (size_t)4*NLAY*QS*HID)           // Apart[4][NLAY][QS][HID]
#define HF_OFF  (AP_OFF + (size_t)4*NLAY*QS*HID)          // hfinal[4][HID]
#define FLAG_OFF_FLOATS (HF_OFF + (size_t)1024)
#define NFLAGS 256

// ---------------------------------------------------------------------------
__device__ __forceinline__ float ld_coh_b32(const float* p) {
    float r;
    asm volatile("global_load_dword %0, %1, off sc0 sc1" : "=v"(r) : "v"(p));
    return r;
}
__device__ __forceinline__ void st_coh_b32(float* p, float v) {
    asm volatile("global_store_dword %0, %1, off sc0 sc1" :: "v"(p), "v"(v) : "memory");
}
__device__ __forceinline__ void st_coh_u32(unsigned* p, unsigned v) {
    asm volatile("global_store_dword %0, %1, off sc0 sc1" :: "v"(p), "v"(v) : "memory");
}
__device__ __forceinline__ unsigned uload(const unsigned* p) {
    return __hip_atomic_load(p, __ATOMIC_RELAXED, __HIP_MEMORY_SCOPE_AGENT);
}

#define SBAR()  { __builtin_amdgcn_s_barrier(); __builtin_amdgcn_sched_barrier(0); }
#define LGKM0() { asm volatile("s_waitcnt lgkmcnt(0)" ::: "memory"); __builtin_amdgcn_sched_barrier(0); }
#define VMW0()  { asm volatile("s_waitcnt vmcnt(0)" ::: "memory"); __builtin_amdgcn_sched_barrier(0); }
// Wait own-wave vmem AND pin reg as output so uses can't hoist above (rule 18).
#define WAIT_PIN(reg) { asm volatile("s_waitcnt vmcnt(0)" : "+v"(reg) :: "memory"); \
                        __builtin_amdgcn_sched_barrier(0); }

__device__ __forceinline__ void spin_ge(const unsigned* p, unsigned target, bool* dead) {
    if (*dead) return;
    unsigned it = 0;
    while (uload(p) < target) {
        __builtin_amdgcn_s_sleep(1);
        if (++it > (1u << 20)) { *dead = true; break; }
    }
}

__device__ __forceinline__ float tanh_fast(float x) {
    return 1.f - __fdividef(2.f, __expf(2.f * x) + 1.f);
}

// DPP-FMA: ROW_ROR:i => lane q reads src0 from lane (q-i)&15 (verified R10).
#define FMAC0(ACC, HB, W) \
    asm volatile("v_fmac_f32 %0, %1, %2" : "+v"(ACC) : "v"(HB), "v"(W));
#define FMACR(ACC, HB, W, I) \
    asm volatile("v_fmac_f32_dpp %0, %1, %2 row_ror:" #I " row_mask:0xf bank_mask:0xf" \
                 : "+v"(ACC) : "v"(HB), "v"(W));

#define FMAC_BLOCK(HB, WB) \
    FMAC0(acc0, HB, w[WB+0])      FMACR(acc1, HB, w[WB+1], 1)   \
    FMACR(acc2, HB, w[WB+2], 2)   FMACR(acc3, HB, w[WB+3], 3)   \
    FMACR(acc0, HB, w[WB+4], 4)   FMACR(acc1, HB, w[WB+5], 5)   \
    FMACR(acc2, HB, w[WB+6], 6)   FMACR(acc3, HB, w[WB+7], 7)   \
    FMACR(acc0, HB, w[WB+8], 8)   FMACR(acc1, HB, w[WB+9], 9)   \
    FMACR(acc0, HB, w[WB+10], 10) FMACR(acc1, HB, w[WB+11], 11) \
    FMACR(acc2, HB, w[WB+12], 12) FMACR(acc3, HB, w[WB+13], 13) \
    FMACR(acc2, HB, w[WB+14], 14) FMACR(acc3, HB, w[WB+15], 15)

#define BPERM4(H) \
    { hb0 = __int_as_float(__builtin_amdgcn_ds_bpermute(ab0, __float_as_int(H))); \
      hb1 = __int_as_float(__builtin_amdgcn_ds_bpermute(ab1, __float_as_int(H))); \
      hb2 = __int_as_float(__builtin_amdgcn_ds_bpermute(ab2, __float_as_int(H))); \
      hb3 = __int_as_float(__builtin_amdgcn_ds_bpermute(ab3, __float_as_int(H))); }

// ---------------------------------------------------------------------------
// Kernel 1: input projection P[c][t][j] = sum_k Wih0_c[j,k] * x[t,k,c]
__global__ __launch_bounds__(1024) void proj_kernel(
    const float* __restrict__ x, const float* __restrict__ Wlp,
    const float* __restrict__ Wlpv, float* __restrict__ P)
{
    __shared__ float xs[TPB][4][NITEMS];
    const int tid = threadIdx.x;
    const int t0 = blockIdx.x * TPB;

    #pragma unroll
    for (int tt = 0; tt < TPB; ++tt) {
        const float2* src = (const float2*)(x + (size_t)(t0 + tt) * NITEMS * 4);
        float2 v = src[tid];
        int e = 2 * tid;
        xs[tt][e & 3][e >> 2]       = v.x;
        xs[tt][(e + 1) & 3][e >> 2] = v.y;
    }
    __syncthreads();

    const int c = tid >> 8, j = tid & 255;
    const float* W = (c == 1) ? Wlpv : Wlp;
    const float4* row = (const float4*)(W + (size_t)j * NITEMS);
    float acc[TPB] = {0.f, 0.f, 0.f, 0.f};
    #pragma unroll 4
    for (int k4 = 0; k4 < NITEMS / 4; ++k4) {
        float4 w = row[k4];
        #pragma unroll
        for (int tt = 0; tt < TPB; ++tt) {
            float4 xv = *(const float4*)(&xs[tt][c][k4 * 4]);
            acc[tt] = fmaf(w.x, xv.x, fmaf(w.y, xv.y, fmaf(w.z, xv.z, fmaf(w.w, xv.w, acc[tt]))));
        }
    }
    #pragma unroll
    for (int tt = 0; tt < TPB; ++tt)
        P[((size_t)c * SEQL + (t0 + tt)) * HID + j] = acc[tt];
}

// ---------------------------------------------------------------------------
// Kernel 2: layer-pipelined RNN. Chunked handshakes with EARLY-POLL + NEXT-CHUNK
// PREFETCH (exploits the ring's producer lead); one barrier per inner step;
// DPP matvec; bpermute broadcast. 124 blocks = 4 chains x (16 B + 15 A).
__global__ __launch_bounds__(1024) void rnn_pipe(
    const float* __restrict__ lp_Wih,  const float* __restrict__ lp_Whh,
    const float* __restrict__ lp_bih,  const float* __restrict__ lp_bhh,
    const float* __restrict__ lpv_Wih, const float* __restrict__ lpv_Whh,
    const float* __restrict__ lpv_bih, const float* __restrict__ lpv_bhh,
    const float* __restrict__ P, float* __restrict__ Hring,
    float* __restrict__ Apart, float* __restrict__ hfinal,
    unsigned* __restrict__ Hflag, unsigned* __restrict__ Aflag)
{
    __shared__ __align__(16) float part2[2][1024];
    __shared__ int pf_lds[2];   // [0]=next-chunk data ready, [1]=next-chunk bp ok

    const int b = blockIdx.x;
    if (b >= 124) return;
    const int tid = threadIdx.x;

    const int c = b / 31;
    const int r = b % 31;
    const int role = (r < NLAY) ? 0 : 1;
    const int l = (r < NLAY) ? r : (r - NLAY + 1);

    const float* Wih = (c == 1) ? lpv_Wih : lp_Wih;
    const float* Whh = (c == 1) ? lpv_Whh : lp_Whh;
    const float* bih = (c == 1) ? lpv_bih : lp_bih;
    const float* bhh = (c == 1) ? lpv_bhh : lp_bhh;

    const int j    = tid & 255;
    const int c4   = tid >> 8;
    const int lane = tid & 63;
    const int q    = lane & 15;
    const int m    = (c4 << 6) | lane;
    const bool first = ((tid & 192) == 0);
    bool dead = false;

    const int ab0 = 4 * (q);
    const int ab1 = 4 * (16 + q);
    const int ab2 = 4 * (32 + q);
    const int ab3 = 4 * (48 + q);

    if (role == 0) {
        // ===================== B role =====================
        const bool l0 = (l == 0);

        float w[64];
        {
            const float* Wrow = Whh + ((size_t)l * HID + j) * HID;
            #pragma unroll
            for (int bb = 0; bb < 4; ++bb)
                #pragma unroll
                for (int i = 0; i < 16; ++i)
                    w[bb * 16 + i] = Wrow[(c4 << 6) + bb * 16 + ((q - i) & 15)];
        }
        #pragma unroll
        for (int i = 0; i < 64; ++i) asm volatile("" : "+v"(w[i]));

        const float bias_m = bih[l * HID + m] + bhh[l * HID + m];

        const float*    Psrc  = P + (size_t)c * SEQL * HID;
        const float*    apbuf = Apart + ((size_t)(c * NLAY + l) * QS) * HID;
        const unsigned* af    = Aflag + c * NLAY + l;
        unsigned*       myHfl = Hflag + c * NLAY + l;
        const unsigned* consA = Aflag + c * NLAY + l + 1;   // valid when l<15
        float*          Hout  = Hring + ((size_t)(c * NLAY + l) * QS) * HID;
        float*          hfin  = hfinal + (size_t)c * HID;

        float h = 0.f;
        float hb0, hb1, hb2, hb3;
        float ap8[CHUNK], apn[CHUNK];
        bool havePF = false;

        for (int k = 0; k < NCHUNK; ++k) {
            // ---------- chunk top ----------
            int pf2ok = 1;
            if (k >= CHUNK && l < NLAY - 1) pf2ok = pf_lds[1];
            const bool needbar = (!havePF && !l0) || !pf2ok;
            if (needbar) {
                if (tid == 0) {
                    if (!havePF && !l0) spin_ge(af, (unsigned)(k + 1), &dead);
                    if (!pf2ok) spin_ge(consA, (unsigned)(k - 7), &dead);
                }
                SBAR();
            }
            if (havePF) {
                VMW0();
                #pragma unroll
                for (int s = 0; s < CHUNK; ++s) ap8[s] = apn[s];
            } else {
                if (l0) {
                    #pragma unroll
                    for (int s = 0; s < CHUNK; ++s)
                        ap8[s] = Psrc[(size_t)(CHUNK * k + s) * HID + m];
                } else {
                    const int sbase = (k & 7) * CHUNK;
                    #pragma unroll
                    for (int s = 0; s < CHUNK; ++s)
                        ap8[s] = ld_coh_b32(apbuf + (size_t)(sbase + s) * HID + m);
                    VMW0();
                }
            }
            // issue next-chunk polls (non-blocking; checked at s==1)
            unsigned afv = 0u, bpv = 0u;
            const bool pollIn = (!l0) && (k + 1 < NCHUNK);
            const bool pollBp = (l < NLAY - 1) && (k + 1 >= CHUNK) && (k + 1 < NCHUNK);
            if (tid == 64 && pollIn)
                asm volatile("global_load_dword %0, %1, off sc0 sc1" : "=v"(afv) : "v"(af));
            if (tid == 65 && pollBp)
                asm volatile("global_load_dword %0, %1, off sc0 sc1" : "=v"(bpv) : "v"(consA));

            // ---------- 8 inner steps ----------
            #pragma unroll
            for (int s = 0; s < CHUNK; ++s) {
                BPERM4(h);
                float acc0 = 0.f, acc1 = 0.f, acc2 = 0.f, acc3 = 0.f;
                FMAC_BLOCK(hb0, 0)
                FMAC_BLOCK(hb1, 16)
                FMAC_BLOCK(hb2, 32)
                FMAC_BLOCK(hb3, 48)
                part2[s & 1][tid] = (acc0 + acc1) + (acc2 + acc3);
                LGKM0(); SBAR();
                const float* pb = &part2[s & 1][0];
                float p = pb[m] + pb[m + 256] + pb[m + 512] + pb[m + 768];
                h = tanh_fast(p + ap8[s] + bias_m);
                if (first) {
                    if (l < NLAY - 1)
                        st_coh_b32(Hout + (size_t)((k & 7) * CHUNK + s) * HID + m, h);
                    else if (k == NCHUNK - 1 && s == CHUNK - 1)
                        st_coh_b32(hfin + m, h);
                }
                if (s == 1) {
                    if (tid == 64 && pollIn) { WAIT_PIN(afv); pf_lds[0] = (afv >= (unsigned)(k + 2)); }
                    if (tid == 65 && pollBp) { WAIT_PIN(bpv); pf_lds[1] = (bpv >= (unsigned)(k - 6)); }
                }
                if (s == 2) {
                    havePF = false;
                    if (k + 1 < NCHUNK) {
                        const bool b1 = l0 || (pf_lds[0] != 0);
                        if (b1) {
                            havePF = true;
                            if (l0) {
                                #pragma unroll
                                for (int s2 = 0; s2 < CHUNK; ++s2)
                                    apn[s2] = Psrc[(size_t)(CHUNK * (k + 1) + s2) * HID + m];
                            } else {
                                const int nb = ((k + 1) & 7) * CHUNK;
                                #pragma unroll
                                for (int s2 = 0; s2 < CHUNK; ++s2)
                                    apn[s2] = ld_coh_b32(apbuf + (size_t)(nb + s2) * HID + m);
                            }
                        }
                    }
                }
            }
            // ---------- drain + publish ----------
            if (first) VMW0();
            SBAR();
            if (tid == 0) st_coh_u32(myHfl, (unsigned)(k + 1));
        }
    } else {
        // ===================== A role (l = 1..15) =====================
        float w[64];
        {
            const float* Wrow = Wih + ((size_t)(l - 1) * HID + j) * HID;
            #pragma unroll
            for (int bb = 0; bb < 4; ++bb)
                #pragma unroll
                for (int i = 0; i < 16; ++i)
                    w[bb * 16 + i] = Wrow[(c4 << 6) + bb * 16 + ((q - i) & 15)];
        }
        #pragma unroll
        for (int i = 0; i < 64; ++i) asm volatile("" : "+v"(w[i]));

        const float*    Hin    = Hring + ((size_t)(c * NLAY + (l - 1)) * QS) * HID;
        const unsigned* inflag = Hflag + c * NLAY + (l - 1);
        float*          Aout   = Apart + ((size_t)(c * NLAY + l) * QS) * HID;
        unsigned*       myAfl  = Aflag + c * NLAY + l;
        const unsigned* consB  = Hflag + c * NLAY + l;

        float hb0, hb1, hb2, hb3;
        float h8[CHUNK], h8n[CHUNK];
        bool havePF = false;

        for (int k = 0; k < NCHUNK; ++k) {
            // ---------- chunk top ----------
            int pf2ok = 1;
            if (k >= CHUNK) pf2ok = pf_lds[1];
            const bool needbar = !havePF || !pf2ok;
            if (needbar) {
                if (tid == 0) {
                    if (!havePF) spin_ge(inflag, (unsigned)(k + 1), &dead);
                    if (!pf2ok)  spin_ge(consB, (unsigned)(k - 7), &dead);
                }
                SBAR();
            }
            if (havePF) {
                VMW0();
                #pragma unroll
                for (int s = 0; s < CHUNK; ++s) h8[s] = h8n[s];
            } else {
                const float* hbase = Hin + (size_t)(k & 7) * CHUNK * HID + m;
                #pragma unroll
                for (int s = 0; s < CHUNK; ++s)
                    h8[s] = ld_coh_b32(hbase + (size_t)s * HID);
                VMW0();
            }
            unsigned inv = 0u, bpv = 0u;
            const bool pollIn = (k + 1 < NCHUNK);
            const bool pollBp = (k + 1 >= CHUNK) && (k + 1 < NCHUNK);
            if (tid == 64 && pollIn)
                asm volatile("global_load_dword %0, %1, off sc0 sc1" : "=v"(inv) : "v"(inflag));
            if (tid == 65 && pollBp)
                asm volatile("global_load_dword %0, %1, off sc0 sc1" : "=v"(bpv) : "v"(consB));

            // ---------- 8 inner steps ----------
            #pragma unroll
            for (int s = 0; s < CHUNK; ++s) {
                BPERM4(h8[s]);
                float acc0 = 0.f, acc1 = 0.f, acc2 = 0.f, acc3 = 0.f;
                FMAC_BLOCK(hb0, 0)
                FMAC_BLOCK(hb1, 16)
                FMAC_BLOCK(hb2, 32)
                FMAC_BLOCK(hb3, 48)
                part2[s & 1][tid] = (acc0 + acc1) + (acc2 + acc3);
                LGKM0(); SBAR();
                if (first) {
                    const float* pb = &part2[s & 1][0];
                    float p = pb[m] + pb[m + 256] + pb[m + 512] + pb[m + 768];
                    st_coh_b32(Aout + (size_t)((k & 7) * CHUNK + s) * HID + m, p);
                }
                if (s == 1) {
                    if (tid == 64 && pollIn) { WAIT_PIN(inv); pf_lds[0] = (inv >= (unsigned)(k + 2)); }
                    if (tid == 65 && pollBp) { WAIT_PIN(bpv); pf_lds[1] = (bpv >= (unsigned)(k - 6)); }
                }
                if (s == 2) {
                    havePF = false;
                    if (k + 1 < NCHUNK && pf_lds[0] != 0) {
                        havePF = true;
                        const float* nb = Hin + (size_t)((k + 1) & 7) * CHUNK * HID + m;
                        #pragma unroll
                        for (int s2 = 0; s2 < CHUNK; ++s2)
                            h8n[s2] = ld_coh_b32(nb + (size_t)s2 * HID);
                    }
                }
            }
            // ---------- drain + publish ----------
            if (first) VMW0();
            SBAR();
            if (tid == 0) st_coh_u32(myAfl, (unsigned)(k + 1));
        }
    }
}

// ---------------------------------------------------------------------------
// Kernel 3: out = fc_W @ concat(h0..h3) + fc_b
__global__ __launch_bounds__(1024) void fc_kernel(
    const float* __restrict__ hfinal, const float* __restrict__ fcW,
    const float* __restrict__ fcb, float* __restrict__ out)
{
    __shared__ float red[1024];
    const int tid = threadIdx.x;
    float v  = hfinal[tid];
    float p0 = fcW[tid] * v;
    float p1 = fcW[1024 + tid] * v;

    red[tid] = p0; __syncthreads();
    for (int st = 512; st > 0; st >>= 1) { if (tid < st) red[tid] += red[tid + st]; __syncthreads(); }
    if (tid == 0) out[0] = red[0] + fcb[0];
    __syncthreads();
    red[tid] = p1; __syncthreads();
    for (int st = 512; st > 0; st >>= 1) { if (tid < st) red[tid] += red[tid + st]; __syncthreads(); }
    if (tid == 0) out[1] = red[0] + fcb[1];
}

// ---------------------------------------------------------------------------
extern "C" void kernel_launch(void* const* d_in, const int* in_sizes, int n_in,
                              void* d_out, int out_size, void* d_ws, size_t ws_size,
                              hipStream_t stream)
{
    (void)in_sizes; (void)n_in; (void)out_size; (void)ws_size;
    const float* x        = (const float*)d_in[0];
    const float* lp_Wih0  = (const float*)d_in[1];
    const float* lp_Wih   = (const float*)d_in[2];
    const float* lp_Whh   = (const float*)d_in[3];
    const float* lp_bih   = (const float*)d_in[4];
    const float* lp_bhh   = (const float*)d_in[5];
    const float* lpv_Wih0 = (const float*)d_in[6];
    const float* lpv_Wih  = (const float*)d_in[7];
    const float* lpv_Whh  = (const float*)d_in[8];
    const float* lpv_bih  = (const float*)d_in[9];
    const float* lpv_bhh  = (const float*)d_in[10];
    const float* fcW      = (const float*)d_in[11];
    const float* fcb      = (const float*)d_in[12];

    float* ws      = (float*)d_ws;
    float* Pbuf    = ws + P_OFF;
    float* Hring   = ws + H_OFF;
    float* Apart   = ws + AP_OFF;
    float* hfinal  = ws + HF_OFF;
    unsigned* flags = (unsigned*)(ws + FLAG_OFF_FLOATS);

    hipMemsetAsync(flags, 0, NFLAGS * sizeof(unsigned), stream);

    proj_kernel<<<SEQL / TPB, 1024, 0, stream>>>(x, lp_Wih0, lpv_Wih0, Pbuf);

    rnn_pipe<<<124, 1024, 0, stream>>>(lp_Wih, lp_Whh, lp_bih, lp_bhh,
                                       lpv_Wih, lpv_Whh, lpv_bih, lpv_bhh,
                                       Pbuf, Hring, Apart, hfinal,
                                       flags, flags + 64);

    fc_kernel<<<1, 1024, 0, stream>>>(hfinal, fcW, fcb, (float*)d_out);
}